// Round 7
// baseline (5137.745 us; speedup 1.0000x reference)
//
#include <hip/hip_runtime.h>
#include <cmath>

#define DEV __device__ __forceinline__

typedef __attribute__((ext_vector_type(8))) short  short8;
typedef __attribute__((ext_vector_type(8))) unsigned short ushort8;
typedef __attribute__((ext_vector_type(4))) float  f32x4;

DEV float sigm(float x){ return 1.0f/(1.0f + __expf(-x)); }
DEV float tanhx(float x){
  x = fminf(fmaxf(x, -15.0f), 15.0f);
  float e = __expf(2.0f*x);
  return (e - 1.0f)/(e + 1.0f);
}
DEV unsigned short f2bf(float f){
  unsigned u = __float_as_uint(f);
  return (unsigned short)((u + 0x7fffu + ((u>>16)&1u)) >> 16);
}
DEV float bf2f(unsigned short h){ return __uint_as_float(((unsigned)h)<<16); }
DEV void split2(float v, unsigned short& hi, unsigned short& lo){
  hi = f2bf(v); lo = f2bf(v - bf2f(hi));
}

#define GLDS(SRC, DST) __builtin_amdgcn_global_load_lds( \
  (const __attribute__((address_space(1))) unsigned int*)(SRC), \
  (__attribute__((address_space(3))) unsigned int*)(DST), 16, 0, 0)

// ---------------------------------------------------------------------------
// fold conv1 (1x1,3->64) into conv2 (3x3,64->128)
// ---------------------------------------------------------------------------
__global__ __launch_bounds__(256) void k_fold(const float* __restrict__ w1,
    const float* __restrict__ b1, const float* __restrict__ w2,
    const float* __restrict__ b2, float* __restrict__ weff, float* __restrict__ beff)
{
  int tid = threadIdx.x;
  for (int i = tid; i < 3456; i += 256){
    int oc = i / 27, rem = i % 27, c = rem / 9, k = rem % 9;
    float s = 0.f;
    for (int m = 0; m < 64; ++m)
      s += w2[(oc*64 + m)*9 + k] * w1[m*3 + c];
    weff[i] = s;
  }
  for (int i = tid; i < 128; i += 256){
    float s = b2[i];
    for (int m = 0; m < 64; ++m){
      float t = 0.f;
      for (int k = 0; k < 9; ++k) t += w2[(i*64 + m)*9 + k];
      s += t * b1[m];
    }
    beff[i] = s;
  }
}

// ---------------------------------------------------------------------------
// conv weight prep: W9T[k][oc][ic] = bf16split(w[oc][ic][k] * bnscale[oc]),
// bias_eff[oc] = cb*sc + shift.
// ---------------------------------------------------------------------------
__global__ __launch_bounds__(256) void k_prepW(const float* __restrict__ w,
    const float* __restrict__ cb, const float* __restrict__ bng,
    const float* __restrict__ bnb, const float* __restrict__ bnm,
    const float* __restrict__ bnv, int useBN, int OC, int IC,
    unsigned short* __restrict__ WH, unsigned short* __restrict__ WL,
    float* __restrict__ bout)
{
  int idx = blockIdx.x*256 + threadIdx.x;
  int tot = OC*IC*9;
  if (idx < tot){
    int k = idx % 9; int t2 = idx/9; int ic = t2 % IC; int oc = t2/IC;
    float sc = useBN ? bng[oc]*rsqrtf(bnv[oc]+1e-5f) : 1.0f;
    unsigned short h,l; split2(w[idx]*sc, h, l);
    size_t o = ((size_t)k*OC + oc)*IC + ic;
    WH[o]=h; WL[o]=l;
  }
  if (idx < OC){
    float sc = useBN ? bng[idx]*rsqrtf(bnv[idx]+1e-5f) : 1.0f;
    float sh = useBN ? (bnb[idx]-bnm[idx]*sc) : 0.f;
    bout[idx] = cb[idx]*sc + sh;
  }
}

// gemm weight prep: WH/WL[oc][ic] = split(w), b = bih+bhh
__global__ __launch_bounds__(256) void k_prepWg(const float* __restrict__ w,
    const float* __restrict__ b1, const float* __restrict__ b2,
    unsigned short* __restrict__ WH, unsigned short* __restrict__ WL,
    float* __restrict__ bout)
{
  int idx = blockIdx.x*256 + threadIdx.x;
  if (idx < 1024*512){
    unsigned short h,l; split2(w[idx], h, l);
    WH[idx]=h; WL[idx]=l;
  }
  if (idx < 1024) bout[idx] = b1[idx] + b2[idx];
}

// lstm recurrent weight prep: U hi/lo split [dir][g][k]  (whh is (1024,256))
__global__ __launch_bounds__(256) void k_prepU(const float* __restrict__ Uf,
    const float* __restrict__ Ub, unsigned short* __restrict__ UHo,
    unsigned short* __restrict__ ULo)
{
  int idx = blockIdx.x*256 + threadIdx.x;        // 2*262144
  if (idx < 524288){
    const float* U = (idx < 262144) ? Uf : Ub;
    unsigned short h,l; split2(U[idx & 262143], h, l);
    UHo[idx] = h; ULo[idx] = l;
  }
}

// ---------------------------------------------------------------------------
// fused conv2' (3x3,IC=3,OC=128) + maxpool2x2/2 -> p1 NHWC bf16 hi/lo (per half)
// ---------------------------------------------------------------------------
__global__ __launch_bounds__(256) void k_conv2pool(const float* __restrict__ x,
    const float* __restrict__ weff, const float* __restrict__ beff,
    unsigned short* __restrict__ p1H, unsigned short* __restrict__ p1L)
{
  __shared__ float wl[8*27];
  __shared__ float sm[8][4][66];
  int tx = threadIdx.x & 63, ty = threadIdx.x >> 6;
  int ocb = blockIdx.z & 15, n = blockIdx.z >> 4;   // n local 0..7
  int oc0 = ocb*8;
  if (threadIdx.x < 216) wl[threadIdx.x] = weff[oc0*27 + threadIdx.x];
  __syncthreads();
  int ow = blockIdx.x*64 + tx;
  int oh = blockIdx.y*4 + ty;
  int owc = min(ow, 509), ohc = min(oh, 61);
  const float* xp = x + ((size_t)n*3*64 + ohc)*512 + owc;
  float iv[27];
  #pragma unroll
  for (int c = 0; c < 3; ++c)
    #pragma unroll
    for (int kh = 0; kh < 3; ++kh)
      #pragma unroll
      for (int kw = 0; kw < 3; ++kw)
        iv[c*9 + kh*3 + kw] = xp[((size_t)c*64 + kh)*512 + kw];
  #pragma unroll
  for (int j = 0; j < 8; ++j){
    float s = beff[oc0 + j];
    const float* wp = &wl[j*27];
    #pragma unroll
    for (int k = 0; k < 27; ++k) s += iv[k]*wp[k];
    sm[j][ty][tx] = s;
  }
  __syncthreads();
  int pr0 = blockIdx.y*2, pc0 = blockIdx.x*32;
  for (int i = threadIdx.x; i < 512; i += 256){
    int pc = i & 31, rem = i >> 5, q = rem & 1, j = rem >> 1;
    int prow = pr0 + q, pcol = pc0 + pc;
    if (prow < 31 && pcol < 255){
      float m0 = fmaxf(sm[j][2*q  ][2*pc], sm[j][2*q  ][2*pc+1]);
      float m1 = fmaxf(sm[j][2*q+1][2*pc], sm[j][2*q+1][2*pc+1]);
      unsigned short h,l; split2(fmaxf(m0,m1), h, l);
      size_t o = (((size_t)(n*31 + prow)*255 + pcol)<<7) + oc0 + j;
      p1H[o] = h; p1L[o] = l;
    }
  }
}

// ---------------------------------------------------------------------------
// split-bf16 implicit-GEMM conv / GEMM.  C[pix][oc] = sum_{k9,ic} A*W.
// BM=128 pix (1 oh row), BN=128 oc, BK=32. 256 thr / 4 waves, mfma 16x16x32.
// ---------------------------------------------------------------------------
__global__ __launch_bounds__(256) void k_igemm(
    const unsigned short* __restrict__ inH, const unsigned short* __restrict__ inL,
    const unsigned short* __restrict__ wH,  const unsigned short* __restrict__ wL,
    const float* __restrict__ bias,
    unsigned short* __restrict__ outH, unsigned short* __restrict__ outL,
    float* __restrict__ outF,
    int IH, int IW, int IC, int OC, int OH, int OW,
    int K9, int sub, int nICc)
{
  __shared__ unsigned short lds[2][16384];  // [AH 4096][AL 4096][BH 4096][BL 4096]
  const int tid  = threadIdx.x;
  const int wv   = tid >> 6, lane = tid & 63;
  const int wr   = wv >> 1,  wc   = wv & 1;
  const int kg   = lane >> 4;
  const int ocTiles = OC >> 7;
  const int ow0 = blockIdx.x << 7;
  const int oh  = blockIdx.y;
  const int ocb = blockIdx.z % ocTiles;
  const int n   = blockIdx.z / ocTiles;
  const int oc0 = ocb << 7;

  const int sp = tid >> 2, ss = tid & 3;
  size_t aBase[2], bBase[2];
  #pragma unroll
  for (int q = 0; q < 2; ++q){
    int p = q*64 + sp;
    int opix = min(ow0 + p, OW-1);
    int sw = ss ^ ((p>>1)&3);
    aBase[q] = ((size_t)(n*IH + (oh<<sub))*IW + ((size_t)opix<<sub))*IC + sw*8;
    int o = q*64 + sp;
    int swb = ss ^ ((o>>1)&3);
    bBase[q] = (size_t)(oc0 + o)*IC + swb*8;
  }
  int aoff[4], boff[4];
  #pragma unroll
  for (int mi = 0; mi < 4; ++mi){
    int pr = wr*64 + mi*16 + (lane&15);
    aoff[mi] = pr*32 + ((kg ^ ((pr>>1)&3))*8);
  }
  #pragma unroll
  for (int nj = 0; nj < 4; ++nj){
    int orow = wc*64 + nj*16 + (lane&15);
    boff[nj] = orow*32 + ((kg ^ ((orow>>1)&3))*8);
  }

  auto STAGE = [&](int buf, int kk, int ic0){
    size_t aOff = ((size_t)((kk/3)*IW + (kk%3)))*IC + ic0;
    size_t bOff = ((size_t)kk*OC)*IC + ic0;
    unsigned short* d0 = &lds[buf][wv*512];
    #pragma unroll
    for (int q = 0; q < 2; ++q){
      GLDS(inH + aBase[q] + aOff, d0 + q*2048);
      GLDS(inL + aBase[q] + aOff, d0 + 4096  + q*2048);
      GLDS(wH  + bBase[q] + bOff, d0 + 8192  + q*2048);
      GLDS(wL  + bBase[q] + bOff, d0 + 12288 + q*2048);
    }
  };

  f32x4 acc[4][4] = {};
  const int NT = K9 * nICc;
  STAGE(0, 0, 0);
  int cur = 0;
  for (int t = 0; t < NT; ++t){
    __syncthreads();
    short8 aH[4], aL[4], bH[4], bL[4];
    #pragma unroll
    for (int mi = 0; mi < 4; ++mi){
      aH[mi] = *(const short8*)&lds[cur][aoff[mi]];
      aL[mi] = *(const short8*)&lds[cur][4096 + aoff[mi]];
    }
    #pragma unroll
    for (int nj = 0; nj < 4; ++nj){
      bH[nj] = *(const short8*)&lds[cur][8192  + boff[nj]];
      bL[nj] = *(const short8*)&lds[cur][12288 + boff[nj]];
    }
    if (t+1 < NT){
      int tn = t+1, kk = tn / nICc, icc = tn - kk*nICc;
      STAGE(cur^1, kk, icc*32);
    }
    #pragma unroll
    for (int mi = 0; mi < 4; ++mi)
      #pragma unroll
      for (int nj = 0; nj < 4; ++nj){
        acc[mi][nj] = __builtin_amdgcn_mfma_f32_16x16x32_bf16(aH[mi], bH[nj], acc[mi][nj],0,0,0);
        acc[mi][nj] = __builtin_amdgcn_mfma_f32_16x16x32_bf16(aL[mi], bH[nj], acc[mi][nj],0,0,0);
        acc[mi][nj] = __builtin_amdgcn_mfma_f32_16x16x32_bf16(aH[mi], bL[nj], acc[mi][nj],0,0,0);
      }
    cur ^= 1;
  }

  const int ocL = oc0 + wc*64 + (lane&15);
  const int rb  = wr*64 + ((lane>>4)<<2);
  #pragma unroll
  for (int nj = 0; nj < 4; ++nj){
    int oc = ocL + nj*16;
    float bs = bias[oc];
    #pragma unroll
    for (int mi = 0; mi < 4; ++mi)
      #pragma unroll
      for (int j = 0; j < 4; ++j){
        int pix = ow0 + rb + mi*16 + j;
        if (pix < OW){
          size_t oi = ((size_t)(n*OH + oh)*OW + pix)*OC + oc;
          float v = acc[mi][nj][j] + bs;
          if (outF) outF[oi] = v;
          else { unsigned short h,l; split2(v,h,l); outH[oi]=h; outL[oi]=l; }
        }
      }
  }
}

// ---------------------------------------------------------------------------
// maxpool 2x2/1 on NHWC bf16 hi/lo, per half: (8,27,251,256)->(8,26,250,256)
// ---------------------------------------------------------------------------
__global__ __launch_bounds__(256) void k_pool2(const unsigned short* __restrict__ yH,
    const unsigned short* __restrict__ yL,
    unsigned short* __restrict__ pH, unsigned short* __restrict__ pL)
{
  int idx = blockIdx.x*256 + threadIdx.x;       // over 8*26*250*32
  if (idx >= 1664000) return;
  int g = idx & 31; int t2 = idx >> 5;
  int pw = t2 % 250; t2 /= 250; int ph = t2 % 26; int n = t2 / 26;
  size_t base = (((size_t)(n*27 + ph)*251 + pw)<<8) + g*8;
  float v[8];
  #pragma unroll
  for (int e = 0; e < 8; ++e) v[e] = -3.4e38f;
  #pragma unroll
  for (int r = 0; r < 2; ++r)
    #pragma unroll
    for (int c = 0; c < 2; ++c){
      size_t o = base + ((size_t)(r*251 + c)<<8);
      ushort8 hv = *(const ushort8*)&yH[o];
      ushort8 lv = *(const ushort8*)&yL[o];
      #pragma unroll
      for (int e = 0; e < 8; ++e)
        v[e] = fmaxf(v[e], bf2f(hv[e]) + bf2f(lv[e]));
    }
  ushort8 oh8, ol8;
  #pragma unroll
  for (int e = 0; e < 8; ++e){ unsigned short h,l; split2(v[e],h,l); oh8[e]=h; ol8[e]=l; }
  size_t ob = (((size_t)(n*26 + ph)*250 + pw)<<8) + g*8;
  *(ushort8*)&pH[ob] = oh8;
  *(ushort8*)&pL[ob] = ol8;
}

// ---------------------------------------------------------------------------
// MFMA bidirectional LSTM. 20 blocks = 10 row-blocks x 2 dirs; 1024 thr/16 waves.
// Block owns 16 sequences. Per step: gates(16x1024) = h(16x256)@U^T via
// mfma 16x16x32 bf16; h AND U split hi/lo, 3 products (≈fp32 precision).
// h fragments kept in LDS in exact MFMA A-fragment layout (conflict-free).
// Gate nonlinearity: thread owns (row, 4 consecutive j); c-state in regs.
// ---------------------------------------------------------------------------
__global__ __launch_bounds__(1024) void k_lstm(const float* __restrict__ pre,
    const unsigned short* __restrict__ UHg, const unsigned short* __restrict__ ULg,
    float* __restrict__ out)
{
  __shared__ float gl[16*1028];                 // gates fp32, padded stride
  __shared__ unsigned short hAh[4096];          // h hi frags [kc][lane][8]
  __shared__ unsigned short hAl[4096];          // h lo frags
  const int t   = threadIdx.x;
  const int b   = blockIdx.x;
  const int dir = b & 1, rbk = b >> 1;
  const int r0  = rbk * 16;
  const int w   = t >> 6, l = t & 63;
  // MFMA-phase coords
  const int g0   = w * 64;
  const int colL = l & 15, kgL = l >> 4;
  // gate-phase coords: thread -> (row, j0..j0+3), aligned to fragment layout
  const int lam  = (t >> 1) & 63;
  const int grow = lam & 15;
  const int kcG  = t >> 7;
  const int half = t & 1;
  const int j0   = kcG*32 + (lam >> 4)*8 + half*4;

  const float* preD = pre + (size_t)dir*19988480ull
                    + ((size_t)(r0 + grow)*122)*1024 + j0;
  float* outD = out + ((size_t)(r0 + grow)*122)*512 + dir*256 + j0;
  const unsigned short* bptH = UHg + (size_t)dir*262144 + (size_t)(g0 + colL)*256 + kgL*8;
  const unsigned short* bptL = ULg + (size_t)dir*262144 + (size_t)(g0 + colL)*256 + kgL*8;
  const int hIdx = kcG*512 + lam*8 + half*4;    // hA write slot (ushorts)

  // zero h fragments (h0 = 0): 1024 thr x 4 ushorts = 4096 exact cover
  {
    uint2 z{0,0};
    *(uint2*)&hAh[t*4] = z;
    *(uint2*)&hAl[t*4] = z;
  }
  __syncthreads();

  float c0 = 0.f, c1 = 0.f, c2 = 0.f, c3 = 0.f;

  for (int s = 0; s < 122; ++s){
    const int tt = dir ? (121 - s) : s;
    // prefetch pre-activations (HBM) early
    const float* pp = preD + (size_t)tt*1024;
    float4 pg0 = *(const float4*)(pp);
    float4 pg1 = *(const float4*)(pp + 256);
    float4 pg2 = *(const float4*)(pp + 512);
    float4 pg3 = *(const float4*)(pp + 768);

    // ---- MFMA phase: acc = (hH+hL) @ (UH+UL), 3-product split ----
    f32x4 acc0 = {}, acc1 = {}, acc2 = {}, acc3 = {};
    #pragma unroll
    for (int kc = 0; kc < 8; ++kc){
      short8 Ah = *(const short8*)&hAh[kc*512 + l*8];
      short8 Al = *(const short8*)&hAl[kc*512 + l*8];
      short8 B0h = *(const short8*)(bptH +         kc*32);
      short8 B1h = *(const short8*)(bptH +  4096 + kc*32);
      short8 B2h = *(const short8*)(bptH +  8192 + kc*32);
      short8 B3h = *(const short8*)(bptH + 12288 + kc*32);
      short8 B0l = *(const short8*)(bptL +         kc*32);
      short8 B1l = *(const short8*)(bptL +  4096 + kc*32);
      short8 B2l = *(const short8*)(bptL +  8192 + kc*32);
      short8 B3l = *(const short8*)(bptL + 12288 + kc*32);
      acc0 = __builtin_amdgcn_mfma_f32_16x16x32_bf16(Ah, B0h, acc0, 0,0,0);
      acc0 = __builtin_amdgcn_mfma_f32_16x16x32_bf16(Al, B0h, acc0, 0,0,0);
      acc0 = __builtin_amdgcn_mfma_f32_16x16x32_bf16(Ah, B0l, acc0, 0,0,0);
      acc1 = __builtin_amdgcn_mfma_f32_16x16x32_bf16(Ah, B1h, acc1, 0,0,0);
      acc1 = __builtin_amdgcn_mfma_f32_16x16x32_bf16(Al, B1h, acc1, 0,0,0);
      acc1 = __builtin_amdgcn_mfma_f32_16x16x32_bf16(Ah, B1l, acc1, 0,0,0);
      acc2 = __builtin_amdgcn_mfma_f32_16x16x32_bf16(Ah, B2h, acc2, 0,0,0);
      acc2 = __builtin_amdgcn_mfma_f32_16x16x32_bf16(Al, B2h, acc2, 0,0,0);
      acc2 = __builtin_amdgcn_mfma_f32_16x16x32_bf16(Ah, B2l, acc2, 0,0,0);
      acc3 = __builtin_amdgcn_mfma_f32_16x16x32_bf16(Ah, B3h, acc3, 0,0,0);
      acc3 = __builtin_amdgcn_mfma_f32_16x16x32_bf16(Al, B3h, acc3, 0,0,0);
      acc3 = __builtin_amdgcn_mfma_f32_16x16x32_bf16(Ah, B3l, acc3, 0,0,0);
    }
    // write gates to LDS: C row = kgL*4+q, col = g0 + nt*16 + colL
    {
      const int rbase = kgL*4;
      #pragma unroll
      for (int q = 0; q < 4; ++q){
        gl[(rbase+q)*1028 + g0 +  0 + colL] = acc0[q];
        gl[(rbase+q)*1028 + g0 + 16 + colL] = acc1[q];
        gl[(rbase+q)*1028 + g0 + 32 + colL] = acc2[q];
        gl[(rbase+q)*1028 + g0 + 48 + colL] = acc3[q];
      }
    }
    __syncthreads();

    // ---- gate phase ----
    float4 gi = *(const float4*)&gl[grow*1028 +       j0];
    float4 gf = *(const float4*)&gl[grow*1028 + 256 + j0];
    float4 gg = *(const float4*)&gl[grow*1028 + 512 + j0];
    float4 go = *(const float4*)&gl[grow*1028 + 768 + j0];
    float h0,h1,h2,h3;
    {
      float i_ = sigm(gi.x + pg0.x), f_ = sigm(gf.x + pg1.x);
      float g_ = tanhx(gg.x + pg2.x), o_ = sigm(go.x + pg3.x);
      c0 = f_*c0 + i_*g_;  h0 = o_*tanhx(c0);
    }{
      float i_ = sigm(gi.y + pg0.y), f_ = sigm(gf.y + pg1.y);
      float g_ = tanhx(gg.y + pg2.y), o_ = sigm(go.y + pg3.y);
      c1 = f_*c1 + i_*g_;  h1 = o_*tanhx(c1);
    }{
      float i_ = sigm(gi.z + pg0.z), f_ = sigm(gf.z + pg1.z);
      float g_ = tanhx(gg.z + pg2.z), o_ = sigm(go.z + pg3.z);
      c2 = f_*c2 + i_*g_;  h2 = o_*tanhx(c2);
    }{
      float i_ = sigm(gi.w + pg0.w), f_ = sigm(gf.w + pg1.w);
      float g_ = tanhx(gg.w + pg2.w), o_ = sigm(go.w + pg3.w);
      c3 = f_*c3 + i_*g_;  h3 = o_*tanhx(c3);
    }
    // output (fp32)
    *(float4*)(outD + (size_t)tt*512) = make_float4(h0,h1,h2,h3);
    // h -> split bf16 fragments
    unsigned short hh[4], hl[4];
    split2(h0, hh[0], hl[0]); split2(h1, hh[1], hl[1]);
    split2(h2, hh[2], hl[2]); split2(h3, hh[3], hl[3]);
    *(uint2*)&hAh[hIdx] = *(uint2*)hh;
    *(uint2*)&hAl[hIdx] = *(uint2*)hl;
    __syncthreads();
  }
}

// ---------------------------------------------------------------------------
// host.  ws layout (float units), peak ~51.44M floats = 206 MB:
//  pre @0 (39.98M) | conv arena (per batch-half, reused): y3@0, y4@15.1M,
//  p1@29.0M, p2@0, p3@15.1M | rowsLo @40.0M | UH@45.1M UL@45.38M | W @45.65M+
// ---------------------------------------------------------------------------
extern "C" void kernel_launch(void* const* d_in, const int* in_sizes, int n_in,
                              void* d_out, int out_size, void* d_ws, size_t ws_size,
                              hipStream_t stream)
{
  const float* x    = (const float*)d_in[0];
  const float* c1w  = (const float*)d_in[1];
  const float* c1b  = (const float*)d_in[2];
  const float* c2w  = (const float*)d_in[3];
  const float* c2b  = (const float*)d_in[4];
  const float* c3w  = (const float*)d_in[5];
  const float* c3b  = (const float*)d_in[6];
  const float* bn1g = (const float*)d_in[7];
  const float* bn1b = (const float*)d_in[8];
  const float* bn1m = (const float*)d_in[9];
  const float* bn1v = (const float*)d_in[10];
  const float* c4w  = (const float*)d_in[11];
  const float* c4b  = (const float*)d_in[12];
  const float* c5w  = (const float*)d_in[13];
  const float* c5b  = (const float*)d_in[14];
  const float* bn2g = (const float*)d_in[15];
  const float* bn2b = (const float*)d_in[16];
  const float* bn2m = (const float*)d_in[17];
  const float* bn2v = (const float*)d_in[18];
  const float* c6w  = (const float*)d_in[19];
  const float* c6b  = (const float*)d_in[20];
  const float* bn3g = (const float*)d_in[21];
  const float* bn3b = (const float*)d_in[22];
  const float* bn3m = (const float*)d_in[23];
  const float* bn3v = (const float*)d_in[24];
  const float* wihf = (const float*)d_in[25];
  const float* whhf = (const float*)d_in[26];
  const float* bihf = (const float*)d_in[27];
  const float* bhhf = (const float*)d_in[28];
  const float* wihb = (const float*)d_in[29];
  const float* whhb = (const float*)d_in[30];
  const float* bihb = (const float*)d_in[31];
  const float* bhhb = (const float*)d_in[32];

  float* ws = (float*)d_ws;
  typedef unsigned short u16;

  float* pre  = ws;                                   // 39,976,960 f
  u16*   y3H  = (u16*)(ws);            u16* y3L = y3H + 15026176ull;
  u16*   y4H  = (u16*)(ws + 15100000ull); u16* y4L = y4H + 13879296ull;
  u16*   p1H  = (u16*)(ws + 29000000ull); u16* p1L = p1H + 8094720ull;
  u16*   p2H  = (u16*)(ws);            u16* p2L = p2H + 13312000ull;
  u16*   p3H  = (u16*)(ws + 15100000ull); u16* p3L = p3H + 6094848ull;
  u16*   rowsL= (u16*)(ws + 40000000ull);             // 9,994,240 u
  u16*   UHd  = (u16*)(ws + 45100000ull);             // 524,288 u (262,144 f)
  u16*   ULd  = (u16*)(ws + 45380000ull);             // 524,288 u (262,144 f)
  u16*   W3H  = (u16*)(ws + 45650000ull); u16* W3L = (u16*)(ws + 45800000ull);
  u16*   W4H  = (u16*)(ws + 45950000ull); u16* W4L = (u16*)(ws + 46250000ull);
  u16*   W5H  = (u16*)(ws + 46550000ull); u16* W5L = (u16*)(ws + 47150000ull);
  u16*   W6H  = (u16*)(ws + 47750000ull); u16* W6L = (u16*)(ws + 48950000ull);
  u16*   WgfH = (u16*)(ws + 50150000ull); u16* WgfL = (u16*)(ws + 50450000ull);
  u16*   WgbH = (u16*)(ws + 50750000ull); u16* WgbL = (u16*)(ws + 51050000ull);
  float* b3   = ws + 51350000ull;
  float* b4   = ws + 51360000ull;
  float* b5   = ws + 51370000ull;
  float* b6   = ws + 51380000ull;
  float* bgf  = ws + 51390000ull;
  float* bgb  = ws + 51400000ull;
  float* weff = ws + 51420000ull;
  float* beff = ws + 51430000ull;
  u16*   rowsH = (u16*)d_out;                         // 9,994,240 u (in d_out)
  float* outF  = (float*)d_out;

  // ---- weight preparation ----
  k_fold<<<1, 256, 0, stream>>>(c1w, c1b, c2w, c2b, weff, beff);
  k_prepW<<<1152, 256, 0, stream>>>(c3w, c3b, bn1g,bn1b,bn1m,bn1v, 1, 256,128, W3H,W3L, b3);
  k_prepW<<<2304, 256, 0, stream>>>(c4w, c4b, nullptr,nullptr,nullptr,nullptr, 0, 256,256, W4H,W4L, b4);
  k_prepW<<<4608, 256, 0, stream>>>(c5w, c5b, bn2g,bn2b,bn2m,bn2v, 1, 512,256, W5H,W5L, b5);
  k_prepW<<<9216, 256, 0, stream>>>(c6w, c6b, bn3g,bn3b,bn3m,bn3v, 1, 512,512, W6H,W6L, b6);
  k_prepWg<<<2048, 256, 0, stream>>>(wihf, bihf, bhhf, WgfH, WgfL, bgf);
  k_prepWg<<<2048, 256, 0, stream>>>(wihb, bihb, bhhb, WgbH, WgbL, bgb);
  k_prepU<<<2048, 256, 0, stream>>>(whhf, whhb, UHd, ULd);

  // ---- conv chain, two batch-halves of 8 images ----
  for (int hb = 0; hb < 2; ++hb){
    int nB = hb*8;
    const float* xh = x + (size_t)nB*98304ull;
    k_conv2pool<<<dim3(8,16,128), 256, 0, stream>>>(xh, weff, beff, p1H, p1L);
    k_igemm<<<dim3(2,29,16), 256, 0, stream>>>(p1H,p1L, W3H,W3L, b3,
        y3H,y3L, nullptr, 31,255,128,256,29,253, 9,0,4);
    k_igemm<<<dim3(2,27,16), 256, 0, stream>>>(y3H,y3L, W4H,W4L, b4,
        y4H,y4L, nullptr, 29,253,256,256,27,251, 9,0,8);
    k_pool2<<<6500, 256, 0, stream>>>(y4H,y4L, p2H,p2L);
    k_igemm<<<dim3(1,12,32), 256, 0, stream>>>(p2H,p2L, W5H,W5L, b5,
        p3H,p3L, nullptr, 26,250,256,512,12,124, 9,1,8);
    k_igemm<<<dim3(1,10,32), 256, 0, stream>>>(p3H,p3L, W6H,W6L, b6,
        rowsH + (size_t)nB*624640ull, rowsL + (size_t)nB*624640ull, nullptr,
        12,124,512,512,10,122, 9,0,16);
  }

  // ---- input projection GEMMs: rows(19520x512) @ W^T(512x1024) -> pre fp32 ----
  k_igemm<<<dim3(153,1,8), 256, 0, stream>>>(rowsH,rowsL, WgfH,WgfL, bgf,
      nullptr,nullptr, pre, 1,19520,512,1024,1,19520, 1,0,16);
  k_igemm<<<dim3(153,1,8), 256, 0, stream>>>(rowsH,rowsL, WgbH,WgbL, bgb,
      nullptr,nullptr, pre + 19988480ull, 1,19520,512,1024,1,19520, 1,0,16);

  // ---- recurrence (MFMA, split-U) ----
  k_lstm<<<20, 1024, 0, stream>>>(pre, UHd, ULd, outF);
}

// Round 8
// 5115.231 us; speedup vs baseline: 1.0044x; 1.0044x over previous
//
#include <hip/hip_runtime.h>
#include <cmath>

#define DEV __device__ __forceinline__

typedef __attribute__((ext_vector_type(8))) short  short8;
typedef __attribute__((ext_vector_type(8))) unsigned short ushort8;
typedef __attribute__((ext_vector_type(4))) float  f32x4;

DEV float sigm(float x){ return 1.0f/(1.0f + __expf(-x)); }
DEV float tanhx(float x){
  x = fminf(fmaxf(x, -15.0f), 15.0f);
  float e = __expf(2.0f*x);
  return (e - 1.0f)/(e + 1.0f);
}
DEV unsigned short f2bf(float f){
  unsigned u = __float_as_uint(f);
  return (unsigned short)((u + 0x7fffu + ((u>>16)&1u)) >> 16);
}
DEV float bf2f(unsigned short h){ return __uint_as_float(((unsigned)h)<<16); }
DEV void split2(float v, unsigned short& hi, unsigned short& lo){
  hi = f2bf(v); lo = f2bf(v - bf2f(hi));
}

#define GLDS(SRC, DST) __builtin_amdgcn_global_load_lds( \
  (const __attribute__((address_space(1))) unsigned int*)(SRC), \
  (__attribute__((address_space(3))) unsigned int*)(DST), 16, 0, 0)

// ---------------------------------------------------------------------------
// fold conv1 (1x1,3->64) into conv2 (3x3,64->128)
// ---------------------------------------------------------------------------
__global__ __launch_bounds__(256) void k_fold(const float* __restrict__ w1,
    const float* __restrict__ b1, const float* __restrict__ w2,
    const float* __restrict__ b2, float* __restrict__ weff, float* __restrict__ beff)
{
  int tid = threadIdx.x;
  for (int i = tid; i < 3456; i += 256){
    int oc = i / 27, rem = i % 27, c = rem / 9, k = rem % 9;
    float s = 0.f;
    for (int m = 0; m < 64; ++m)
      s += w2[(oc*64 + m)*9 + k] * w1[m*3 + c];
    weff[i] = s;
  }
  for (int i = tid; i < 128; i += 256){
    float s = b2[i];
    for (int m = 0; m < 64; ++m){
      float t = 0.f;
      for (int k = 0; k < 9; ++k) t += w2[(i*64 + m)*9 + k];
      s += t * b1[m];
    }
    beff[i] = s;
  }
}

// ---------------------------------------------------------------------------
// conv weight prep: W9T[k][oc][ic] = bf16split(w[oc][ic][k] * bnscale[oc]),
// bias_eff[oc] = cb*sc + shift.
// ---------------------------------------------------------------------------
__global__ __launch_bounds__(256) void k_prepW(const float* __restrict__ w,
    const float* __restrict__ cb, const float* __restrict__ bng,
    const float* __restrict__ bnb, const float* __restrict__ bnm,
    const float* __restrict__ bnv, int useBN, int OC, int IC,
    unsigned short* __restrict__ WH, unsigned short* __restrict__ WL,
    float* __restrict__ bout)
{
  int idx = blockIdx.x*256 + threadIdx.x;
  int tot = OC*IC*9;
  if (idx < tot){
    int k = idx % 9; int t2 = idx/9; int ic = t2 % IC; int oc = t2/IC;
    float sc = useBN ? bng[oc]*rsqrtf(bnv[oc]+1e-5f) : 1.0f;
    unsigned short h,l; split2(w[idx]*sc, h, l);
    size_t o = ((size_t)k*OC + oc)*IC + ic;
    WH[o]=h; WL[o]=l;
  }
  if (idx < OC){
    float sc = useBN ? bng[idx]*rsqrtf(bnv[idx]+1e-5f) : 1.0f;
    float sh = useBN ? (bnb[idx]-bnm[idx]*sc) : 0.f;
    bout[idx] = cb[idx]*sc + sh;
  }
}

// gemm weight prep: WH/WL[oc][ic] = split(w), b = bih+bhh
__global__ __launch_bounds__(256) void k_prepWg(const float* __restrict__ w,
    const float* __restrict__ b1, const float* __restrict__ b2,
    unsigned short* __restrict__ WH, unsigned short* __restrict__ WL,
    float* __restrict__ bout)
{
  int idx = blockIdx.x*256 + threadIdx.x;
  if (idx < 1024*512){
    unsigned short h,l; split2(w[idx], h, l);
    WH[idx]=h; WL[idx]=l;
  }
  if (idx < 1024) bout[idx] = b1[idx] + b2[idx];
}

// ---------------------------------------------------------------------------
// lstm recurrent weight prep: U hi/lo split, PRE-SWIZZLED into per-wave MFMA
// B-fragment order:  UF[dir][w(16)][nt(4)][kc(8)][lane(64)][e(8)]
//   gate = w*64 + nt*16 + (lane&15);  k = (lane>>4)*8 + kc*32 + e
// so each wave's 16B/lane load is 1KB contiguous (fully coalesced).
// ---------------------------------------------------------------------------
__global__ __launch_bounds__(256) void k_prepU(const float* __restrict__ Uf,
    const float* __restrict__ Ub, unsigned short* __restrict__ UHo,
    unsigned short* __restrict__ ULo)
{
  int idx = blockIdx.x*256 + threadIdx.x;        // 2*262144
  if (idx < 524288){
    int e  = idx & 7;
    int l  = (idx >> 3) & 63;
    int kc = (idx >> 9) & 7;
    int nt = (idx >> 12) & 3;
    int w  = (idx >> 14) & 15;
    int d  = idx >> 18;
    int gate = w*64 + nt*16 + (l & 15);
    int k    = (l >> 4)*8 + kc*32 + e;
    const float* U = d ? Ub : Uf;
    unsigned short h,lo; split2(U[gate*256 + k], h, lo);
    UHo[idx] = h; ULo[idx] = lo;
  }
}

// ---------------------------------------------------------------------------
// fused conv2' (3x3,IC=3,OC=128) + maxpool2x2/2 -> p1 NHWC bf16 hi/lo (per half)
// ---------------------------------------------------------------------------
__global__ __launch_bounds__(256) void k_conv2pool(const float* __restrict__ x,
    const float* __restrict__ weff, const float* __restrict__ beff,
    unsigned short* __restrict__ p1H, unsigned short* __restrict__ p1L)
{
  __shared__ float wl[8*27];
  __shared__ float sm[8][4][66];
  int tx = threadIdx.x & 63, ty = threadIdx.x >> 6;
  int ocb = blockIdx.z & 15, n = blockIdx.z >> 4;   // n local 0..7
  int oc0 = ocb*8;
  if (threadIdx.x < 216) wl[threadIdx.x] = weff[oc0*27 + threadIdx.x];
  __syncthreads();
  int ow = blockIdx.x*64 + tx;
  int oh = blockIdx.y*4 + ty;
  int owc = min(ow, 509), ohc = min(oh, 61);
  const float* xp = x + ((size_t)n*3*64 + ohc)*512 + owc;
  float iv[27];
  #pragma unroll
  for (int c = 0; c < 3; ++c)
    #pragma unroll
    for (int kh = 0; kh < 3; ++kh)
      #pragma unroll
      for (int kw = 0; kw < 3; ++kw)
        iv[c*9 + kh*3 + kw] = xp[((size_t)c*64 + kh)*512 + kw];
  #pragma unroll
  for (int j = 0; j < 8; ++j){
    float s = beff[oc0 + j];
    const float* wp = &wl[j*27];
    #pragma unroll
    for (int k = 0; k < 27; ++k) s += iv[k]*wp[k];
    sm[j][ty][tx] = s;
  }
  __syncthreads();
  int pr0 = blockIdx.y*2, pc0 = blockIdx.x*32;
  for (int i = threadIdx.x; i < 512; i += 256){
    int pc = i & 31, rem = i >> 5, q = rem & 1, j = rem >> 1;
    int prow = pr0 + q, pcol = pc0 + pc;
    if (prow < 31 && pcol < 255){
      float m0 = fmaxf(sm[j][2*q  ][2*pc], sm[j][2*q  ][2*pc+1]);
      float m1 = fmaxf(sm[j][2*q+1][2*pc], sm[j][2*q+1][2*pc+1]);
      unsigned short h,l; split2(fmaxf(m0,m1), h, l);
      size_t o = (((size_t)(n*31 + prow)*255 + pcol)<<7) + oc0 + j;
      p1H[o] = h; p1L[o] = l;
    }
  }
}

// ---------------------------------------------------------------------------
// split-bf16 implicit-GEMM conv / GEMM.  C[pix][oc] = sum_{k9,ic} A*W.
// BM=128 pix (1 oh row), BN=128 oc, BK=32. 256 thr / 4 waves, mfma 16x16x32.
// ---------------------------------------------------------------------------
__global__ __launch_bounds__(256) void k_igemm(
    const unsigned short* __restrict__ inH, const unsigned short* __restrict__ inL,
    const unsigned short* __restrict__ wH,  const unsigned short* __restrict__ wL,
    const float* __restrict__ bias,
    unsigned short* __restrict__ outH, unsigned short* __restrict__ outL,
    float* __restrict__ outF,
    int IH, int IW, int IC, int OC, int OH, int OW,
    int K9, int sub, int nICc)
{
  __shared__ unsigned short lds[2][16384];  // [AH 4096][AL 4096][BH 4096][BL 4096]
  const int tid  = threadIdx.x;
  const int wv   = tid >> 6, lane = tid & 63;
  const int wr   = wv >> 1,  wc   = wv & 1;
  const int kg   = lane >> 4;
  const int ocTiles = OC >> 7;
  const int ow0 = blockIdx.x << 7;
  const int oh  = blockIdx.y;
  const int ocb = blockIdx.z % ocTiles;
  const int n   = blockIdx.z / ocTiles;
  const int oc0 = ocb << 7;

  const int sp = tid >> 2, ss = tid & 3;
  size_t aBase[2], bBase[2];
  #pragma unroll
  for (int q = 0; q < 2; ++q){
    int p = q*64 + sp;
    int opix = min(ow0 + p, OW-1);
    int sw = ss ^ ((p>>1)&3);
    aBase[q] = ((size_t)(n*IH + (oh<<sub))*IW + ((size_t)opix<<sub))*IC + sw*8;
    int o = q*64 + sp;
    int swb = ss ^ ((o>>1)&3);
    bBase[q] = (size_t)(oc0 + o)*IC + swb*8;
  }
  int aoff[4], boff[4];
  #pragma unroll
  for (int mi = 0; mi < 4; ++mi){
    int pr = wr*64 + mi*16 + (lane&15);
    aoff[mi] = pr*32 + ((kg ^ ((pr>>1)&3))*8);
  }
  #pragma unroll
  for (int nj = 0; nj < 4; ++nj){
    int orow = wc*64 + nj*16 + (lane&15);
    boff[nj] = orow*32 + ((kg ^ ((orow>>1)&3))*8);
  }

  auto STAGE = [&](int buf, int kk, int ic0){
    size_t aOff = ((size_t)((kk/3)*IW + (kk%3)))*IC + ic0;
    size_t bOff = ((size_t)kk*OC)*IC + ic0;
    unsigned short* d0 = &lds[buf][wv*512];
    #pragma unroll
    for (int q = 0; q < 2; ++q){
      GLDS(inH + aBase[q] + aOff, d0 + q*2048);
      GLDS(inL + aBase[q] + aOff, d0 + 4096  + q*2048);
      GLDS(wH  + bBase[q] + bOff, d0 + 8192  + q*2048);
      GLDS(wL  + bBase[q] + bOff, d0 + 12288 + q*2048);
    }
  };

  f32x4 acc[4][4] = {};
  const int NT = K9 * nICc;
  STAGE(0, 0, 0);
  int cur = 0;
  for (int t = 0; t < NT; ++t){
    __syncthreads();
    short8 aH[4], aL[4], bH[4], bL[4];
    #pragma unroll
    for (int mi = 0; mi < 4; ++mi){
      aH[mi] = *(const short8*)&lds[cur][aoff[mi]];
      aL[mi] = *(const short8*)&lds[cur][4096 + aoff[mi]];
    }
    #pragma unroll
    for (int nj = 0; nj < 4; ++nj){
      bH[nj] = *(const short8*)&lds[cur][8192  + boff[nj]];
      bL[nj] = *(const short8*)&lds[cur][12288 + boff[nj]];
    }
    if (t+1 < NT){
      int tn = t+1, kk = tn / nICc, icc = tn - kk*nICc;
      STAGE(cur^1, kk, icc*32);
    }
    #pragma unroll
    for (int mi = 0; mi < 4; ++mi)
      #pragma unroll
      for (int nj = 0; nj < 4; ++nj){
        acc[mi][nj] = __builtin_amdgcn_mfma_f32_16x16x32_bf16(aH[mi], bH[nj], acc[mi][nj],0,0,0);
        acc[mi][nj] = __builtin_amdgcn_mfma_f32_16x16x32_bf16(aL[mi], bH[nj], acc[mi][nj],0,0,0);
        acc[mi][nj] = __builtin_amdgcn_mfma_f32_16x16x32_bf16(aH[mi], bL[nj], acc[mi][nj],0,0,0);
      }
    cur ^= 1;
  }

  const int ocL = oc0 + wc*64 + (lane&15);
  const int rb  = wr*64 + ((lane>>4)<<2);
  #pragma unroll
  for (int nj = 0; nj < 4; ++nj){
    int oc = ocL + nj*16;
    float bs = bias[oc];
    #pragma unroll
    for (int mi = 0; mi < 4; ++mi)
      #pragma unroll
      for (int j = 0; j < 4; ++j){
        int pix = ow0 + rb + mi*16 + j;
        if (pix < OW){
          size_t oi = ((size_t)(n*OH + oh)*OW + pix)*OC + oc;
          float v = acc[mi][nj][j] + bs;
          if (outF) outF[oi] = v;
          else { unsigned short h,l; split2(v,h,l); outH[oi]=h; outL[oi]=l; }
        }
      }
  }
}

// ---------------------------------------------------------------------------
// maxpool 2x2/1 on NHWC bf16 hi/lo, per half: (8,27,251,256)->(8,26,250,256)
// ---------------------------------------------------------------------------
__global__ __launch_bounds__(256) void k_pool2(const unsigned short* __restrict__ yH,
    const unsigned short* __restrict__ yL,
    unsigned short* __restrict__ pH, unsigned short* __restrict__ pL)
{
  int idx = blockIdx.x*256 + threadIdx.x;       // over 8*26*250*32
  if (idx >= 1664000) return;
  int g = idx & 31; int t2 = idx >> 5;
  int pw = t2 % 250; t2 /= 250; int ph = t2 % 26; int n = t2 / 26;
  size_t base = (((size_t)(n*27 + ph)*251 + pw)<<8) + g*8;
  float v[8];
  #pragma unroll
  for (int e = 0; e < 8; ++e) v[e] = -3.4e38f;
  #pragma unroll
  for (int r = 0; r < 2; ++r)
    #pragma unroll
    for (int c = 0; c < 2; ++c){
      size_t o = base + ((size_t)(r*251 + c)<<8);
      ushort8 hv = *(const ushort8*)&yH[o];
      ushort8 lv = *(const ushort8*)&yL[o];
      #pragma unroll
      for (int e = 0; e < 8; ++e)
        v[e] = fmaxf(v[e], bf2f(hv[e]) + bf2f(lv[e]));
    }
  ushort8 oh8, ol8;
  #pragma unroll
  for (int e = 0; e < 8; ++e){ unsigned short h,l; split2(v[e],h,l); oh8[e]=h; ol8[e]=l; }
  size_t ob = (((size_t)(n*26 + ph)*250 + pw)<<8) + g*8;
  *(ushort8*)&pH[ob] = oh8;
  *(ushort8*)&pL[ob] = ol8;
}

// ---------------------------------------------------------------------------
// MFMA bidirectional LSTM. 20 blocks = 10 row-blocks x 2 dirs; 1024 thr/16 waves.
// Block owns 16 sequences. Per step: gates(16x1024) = h(16x256)@U^T via
// mfma 16x16x32 bf16; h AND U split hi/lo, 3 products (≈fp32 precision).
// U is pre-swizzled into per-wave fragment order -> every load is 1KB
// contiguous per wave (coalesced); all 10 blocks/dir share the same 1MB in L2.
// __launch_bounds__(1024,4): 1 block/CU -> 128 VGPRs for load pipelining.
// ---------------------------------------------------------------------------
__global__ __launch_bounds__(1024, 4) void k_lstm(const float* __restrict__ pre,
    const unsigned short* __restrict__ UHg, const unsigned short* __restrict__ ULg,
    float* __restrict__ out)
{
  __shared__ float gl[16*1028];                 // gates fp32, padded stride
  __shared__ unsigned short hAh[4096];          // h hi frags [kc][lane][8]
  __shared__ unsigned short hAl[4096];          // h lo frags
  const int t   = threadIdx.x;
  const int b   = blockIdx.x;
  const int dir = b & 1, rbk = b >> 1;
  const int r0  = rbk * 16;
  const int w   = t >> 6, l = t & 63;
  // MFMA-phase coords
  const int g0   = w * 64;
  const int colL = l & 15, kgL = l >> 4;
  // gate-phase coords: thread -> (row, j0..j0+3), aligned to fragment layout
  const int lam  = (t >> 1) & 63;
  const int grow = lam & 15;
  const int kcG  = t >> 7;
  const int half = t & 1;
  const int j0   = kcG*32 + (lam >> 4)*8 + half*4;

  const float* preD = pre + (size_t)dir*19988480ull
                    + ((size_t)(r0 + grow)*122)*1024 + j0;
  float* outD = out + ((size_t)(r0 + grow)*122)*512 + dir*256 + j0;
  // per-wave fragment bases (coalesced: lane-consecutive 16B)
  const unsigned short* bwH = UHg + (size_t)dir*262144 + (size_t)w*16384 + (size_t)l*8;
  const unsigned short* bwL = ULg + (size_t)dir*262144 + (size_t)w*16384 + (size_t)l*8;
  const int hIdx = kcG*512 + lam*8 + half*4;    // hA write slot (ushorts)

  // zero h fragments (h0 = 0): 1024 thr x 4 ushorts = 4096 exact cover
  {
    uint2 z{0,0};
    *(uint2*)&hAh[t*4] = z;
    *(uint2*)&hAl[t*4] = z;
  }
  __syncthreads();

  float c0 = 0.f, c1 = 0.f, c2 = 0.f, c3 = 0.f;

  for (int s = 0; s < 122; ++s){
    const int tt = dir ? (121 - s) : s;
    // prefetch pre-activations (HBM) early
    const float* pp = preD + (size_t)tt*1024;
    float4 pg0 = *(const float4*)(pp);
    float4 pg1 = *(const float4*)(pp + 256);
    float4 pg2 = *(const float4*)(pp + 512);
    float4 pg3 = *(const float4*)(pp + 768);

    // ---- MFMA phase: acc = (hH+hL) @ (UH+UL), 3-product split ----
    f32x4 acc0 = {}, acc1 = {}, acc2 = {}, acc3 = {};
    #pragma unroll
    for (int kc = 0; kc < 8; ++kc){
      short8 Ah = *(const short8*)&hAh[kc*512 + l*8];
      short8 Al = *(const short8*)&hAl[kc*512 + l*8];
      short8 B0h = *(const short8*)(bwH +         kc*512);
      short8 B1h = *(const short8*)(bwH +  4096 + kc*512);
      short8 B2h = *(const short8*)(bwH +  8192 + kc*512);
      short8 B3h = *(const short8*)(bwH + 12288 + kc*512);
      short8 B0l = *(const short8*)(bwL +         kc*512);
      short8 B1l = *(const short8*)(bwL +  4096 + kc*512);
      short8 B2l = *(const short8*)(bwL +  8192 + kc*512);
      short8 B3l = *(const short8*)(bwL + 12288 + kc*512);
      acc0 = __builtin_amdgcn_mfma_f32_16x16x32_bf16(Ah, B0h, acc0, 0,0,0);
      acc0 = __builtin_amdgcn_mfma_f32_16x16x32_bf16(Al, B0h, acc0, 0,0,0);
      acc0 = __builtin_amdgcn_mfma_f32_16x16x32_bf16(Ah, B0l, acc0, 0,0,0);
      acc1 = __builtin_amdgcn_mfma_f32_16x16x32_bf16(Ah, B1h, acc1, 0,0,0);
      acc1 = __builtin_amdgcn_mfma_f32_16x16x32_bf16(Al, B1h, acc1, 0,0,0);
      acc1 = __builtin_amdgcn_mfma_f32_16x16x32_bf16(Ah, B1l, acc1, 0,0,0);
      acc2 = __builtin_amdgcn_mfma_f32_16x16x32_bf16(Ah, B2h, acc2, 0,0,0);
      acc2 = __builtin_amdgcn_mfma_f32_16x16x32_bf16(Al, B2h, acc2, 0,0,0);
      acc2 = __builtin_amdgcn_mfma_f32_16x16x32_bf16(Ah, B2l, acc2, 0,0,0);
      acc3 = __builtin_amdgcn_mfma_f32_16x16x32_bf16(Ah, B3h, acc3, 0,0,0);
      acc3 = __builtin_amdgcn_mfma_f32_16x16x32_bf16(Al, B3h, acc3, 0,0,0);
      acc3 = __builtin_amdgcn_mfma_f32_16x16x32_bf16(Ah, B3l, acc3, 0,0,0);
    }
    // write gates to LDS: C row = kgL*4+q, col = g0 + nt*16 + colL
    {
      const int rbase = kgL*4;
      #pragma unroll
      for (int q = 0; q < 4; ++q){
        gl[(rbase+q)*1028 + g0 +  0 + colL] = acc0[q];
        gl[(rbase+q)*1028 + g0 + 16 + colL] = acc1[q];
        gl[(rbase+q)*1028 + g0 + 32 + colL] = acc2[q];
        gl[(rbase+q)*1028 + g0 + 48 + colL] = acc3[q];
      }
    }
    __syncthreads();

    // ---- gate phase ----
    float4 gi = *(const float4*)&gl[grow*1028 +       j0];
    float4 gf = *(const float4*)&gl[grow*1028 + 256 + j0];
    float4 gg = *(const float4*)&gl[grow*1028 + 512 + j0];
    float4 go = *(const float4*)&gl[grow*1028 + 768 + j0];
    float h0,h1,h2,h3;
    {
      float i_ = sigm(gi.x + pg0.x), f_ = sigm(gf.x + pg1.x);
      float g_ = tanhx(gg.x + pg2.x), o_ = sigm(go.x + pg3.x);
      c0 = f_*c0 + i_*g_;  h0 = o_*tanhx(c0);
    }{
      float i_ = sigm(gi.y + pg0.y), f_ = sigm(gf.y + pg1.y);
      float g_ = tanhx(gg.y + pg2.y), o_ = sigm(go.y + pg3.y);
      c1 = f_*c1 + i_*g_;  h1 = o_*tanhx(c1);
    }{
      float i_ = sigm(gi.z + pg0.z), f_ = sigm(gf.z + pg1.z);
      float g_ = tanhx(gg.z + pg2.z), o_ = sigm(go.z + pg3.z);
      c2 = f_*c2 + i_*g_;  h2 = o_*tanhx(c2);
    }{
      float i_ = sigm(gi.w + pg0.w), f_ = sigm(gf.w + pg1.w);
      float g_ = tanhx(gg.w + pg2.w), o_ = sigm(go.w + pg3.w);
      c3 = f_*c3 + i_*g_;  h3 = o_*tanhx(c3);
    }
    // output (fp32)
    *(float4*)(outD + (size_t)tt*512) = make_float4(h0,h1,h2,h3);
    // h -> split bf16 fragments
    unsigned short hh[4], hl[4];
    split2(h0, hh[0], hl[0]); split2(h1, hh[1], hl[1]);
    split2(h2, hh[2], hl[2]); split2(h3, hh[3], hl[3]);
    *(uint2*)&hAh[hIdx] = *(uint2*)hh;
    *(uint2*)&hAl[hIdx] = *(uint2*)hl;
    __syncthreads();
  }
}

// ---------------------------------------------------------------------------
// host.  ws layout (float units), peak ~51.44M floats = 206 MB:
//  pre @0 (39.98M) | conv arena (per batch-half, reused): y3@0, y4@15.1M,
//  p1@29.0M, p2@0, p3@15.1M | rowsLo @40.0M | UH@45.1M UL@45.38M | W @45.65M+
// ---------------------------------------------------------------------------
extern "C" void kernel_launch(void* const* d_in, const int* in_sizes, int n_in,
                              void* d_out, int out_size, void* d_ws, size_t ws_size,
                              hipStream_t stream)
{
  const float* x    = (const float*)d_in[0];
  const float* c1w  = (const float*)d_in[1];
  const float* c1b  = (const float*)d_in[2];
  const float* c2w  = (const float*)d_in[3];
  const float* c2b  = (const float*)d_in[4];
  const float* c3w  = (const float*)d_in[5];
  const float* c3b  = (const float*)d_in[6];
  const float* bn1g = (const float*)d_in[7];
  const float* bn1b = (const float*)d_in[8];
  const float* bn1m = (const float*)d_in[9];
  const float* bn1v = (const float*)d_in[10];
  const float* c4w  = (const float*)d_in[11];
  const float* c4b  = (const float*)d_in[12];
  const float* c5w  = (const float*)d_in[13];
  const float* c5b  = (const float*)d_in[14];
  const float* bn2g = (const float*)d_in[15];
  const float* bn2b = (const float*)d_in[16];
  const float* bn2m = (const float*)d_in[17];
  const float* bn2v = (const float*)d_in[18];
  const float* c6w  = (const float*)d_in[19];
  const float* c6b  = (const float*)d_in[20];
  const float* bn3g = (const float*)d_in[21];
  const float* bn3b = (const float*)d_in[22];
  const float* bn3m = (const float*)d_in[23];
  const float* bn3v = (const float*)d_in[24];
  const float* wihf = (const float*)d_in[25];
  const float* whhf = (const float*)d_in[26];
  const float* bihf = (const float*)d_in[27];
  const float* bhhf = (const float*)d_in[28];
  const float* wihb = (const float*)d_in[29];
  const float* whhb = (const float*)d_in[30];
  const float* bihb = (const float*)d_in[31];
  const float* bhhb = (const float*)d_in[32];

  float* ws = (float*)d_ws;
  typedef unsigned short u16;

  float* pre  = ws;                                   // 39,976,960 f
  u16*   y3H  = (u16*)(ws);            u16* y3L = y3H + 15026176ull;
  u16*   y4H  = (u16*)(ws + 15100000ull); u16* y4L = y4H + 13879296ull;
  u16*   p1H  = (u16*)(ws + 29000000ull); u16* p1L = p1H + 8094720ull;
  u16*   p2H  = (u16*)(ws);            u16* p2L = p2H + 13312000ull;
  u16*   p3H  = (u16*)(ws + 15100000ull); u16* p3L = p3H + 6094848ull;
  u16*   rowsL= (u16*)(ws + 40000000ull);             // 9,994,240 u
  u16*   UHd  = (u16*)(ws + 45100000ull);             // 524,288 u (swizzled)
  u16*   ULd  = (u16*)(ws + 45380000ull);             // 524,288 u (swizzled)
  u16*   W3H  = (u16*)(ws + 45650000ull); u16* W3L = (u16*)(ws + 45800000ull);
  u16*   W4H  = (u16*)(ws + 45950000ull); u16* W4L = (u16*)(ws + 46250000ull);
  u16*   W5H  = (u16*)(ws + 46550000ull); u16* W5L = (u16*)(ws + 47150000ull);
  u16*   W6H  = (u16*)(ws + 47750000ull); u16* W6L = (u16*)(ws + 48950000ull);
  u16*   WgfH = (u16*)(ws + 50150000ull); u16* WgfL = (u16*)(ws + 50450000ull);
  u16*   WgbH = (u16*)(ws + 50750000ull); u16* WgbL = (u16*)(ws + 51050000ull);
  float* b3   = ws + 51350000ull;
  float* b4   = ws + 51360000ull;
  float* b5   = ws + 51370000ull;
  float* b6   = ws + 51380000ull;
  float* bgf  = ws + 51390000ull;
  float* bgb  = ws + 51400000ull;
  float* weff = ws + 51420000ull;
  float* beff = ws + 51430000ull;
  u16*   rowsH = (u16*)d_out;                         // 9,994,240 u (in d_out)
  float* outF  = (float*)d_out;

  // ---- weight preparation ----
  k_fold<<<1, 256, 0, stream>>>(c1w, c1b, c2w, c2b, weff, beff);
  k_prepW<<<1152, 256, 0, stream>>>(c3w, c3b, bn1g,bn1b,bn1m,bn1v, 1, 256,128, W3H,W3L, b3);
  k_prepW<<<2304, 256, 0, stream>>>(c4w, c4b, nullptr,nullptr,nullptr,nullptr, 0, 256,256, W4H,W4L, b4);
  k_prepW<<<4608, 256, 0, stream>>>(c5w, c5b, bn2g,bn2b,bn2m,bn2v, 1, 512,256, W5H,W5L, b5);
  k_prepW<<<9216, 256, 0, stream>>>(c6w, c6b, bn3g,bn3b,bn3m,bn3v, 1, 512,512, W6H,W6L, b6);
  k_prepWg<<<2048, 256, 0, stream>>>(wihf, bihf, bhhf, WgfH, WgfL, bgf);
  k_prepWg<<<2048, 256, 0, stream>>>(wihb, bihb, bhhb, WgbH, WgbL, bgb);
  k_prepU<<<2048, 256, 0, stream>>>(whhf, whhb, UHd, ULd);

  // ---- conv chain, two batch-halves of 8 images ----
  for (int hb = 0; hb < 2; ++hb){
    int nB = hb*8;
    const float* xh = x + (size_t)nB*98304ull;
    k_conv2pool<<<dim3(8,16,128), 256, 0, stream>>>(xh, weff, beff, p1H, p1L);
    k_igemm<<<dim3(2,29,16), 256, 0, stream>>>(p1H,p1L, W3H,W3L, b3,
        y3H,y3L, nullptr, 31,255,128,256,29,253, 9,0,4);
    k_igemm<<<dim3(2,27,16), 256, 0, stream>>>(y3H,y3L, W4H,W4L, b4,
        y4H,y4L, nullptr, 29,253,256,256,27,251, 9,0,8);
    k_pool2<<<6500, 256, 0, stream>>>(y4H,y4L, p2H,p2L);
    k_igemm<<<dim3(1,12,32), 256, 0, stream>>>(p2H,p2L, W5H,W5L, b5,
        p3H,p3L, nullptr, 26,250,256,512,12,124, 9,1,8);
    k_igemm<<<dim3(1,10,32), 256, 0, stream>>>(p3H,p3L, W6H,W6L, b6,
        rowsH + (size_t)nB*624640ull, rowsL + (size_t)nB*624640ull, nullptr,
        12,124,512,512,10,122, 9,0,16);
  }

  // ---- input projection GEMMs: rows(19520x512) @ W^T(512x1024) -> pre fp32 ----
  k_igemm<<<dim3(153,1,8), 256, 0, stream>>>(rowsH,rowsL, WgfH,WgfL, bgf,
      nullptr,nullptr, pre, 1,19520,512,1024,1,19520, 1,0,16);
  k_igemm<<<dim3(153,1,8), 256, 0, stream>>>(rowsH,rowsL, WgbH,WgbL, bgb,
      nullptr,nullptr, pre + 19988480ull, 1,19520,512,1024,1,19520, 1,0,16);

  // ---- recurrence (MFMA, coalesced fragment-layout U) ----
  k_lstm<<<20, 1024, 0, stream>>>(pre, UHd, ULd, outF);
}

// Round 9
// 3242.566 us; speedup vs baseline: 1.5845x; 1.5775x over previous
//
#include <hip/hip_runtime.h>
#include <cmath>

#define DEV __device__ __forceinline__

typedef __attribute__((ext_vector_type(8))) short  short8;
typedef __attribute__((ext_vector_type(8))) unsigned short ushort8;
typedef __attribute__((ext_vector_type(4))) float  f32x4;
typedef __attribute__((ext_vector_type(8))) _Float16 f16x8;

DEV float sigm(float x){ return 1.0f/(1.0f + __expf(-x)); }
DEV float tanhx(float x){
  x = fminf(fmaxf(x, -15.0f), 15.0f);
  float e = __expf(2.0f*x);
  return (e - 1.0f)/(e + 1.0f);
}
DEV unsigned short f2bf(float f){
  unsigned u = __float_as_uint(f);
  return (unsigned short)((u + 0x7fffu + ((u>>16)&1u)) >> 16);
}
DEV float bf2f(unsigned short h){ return __uint_as_float(((unsigned)h)<<16); }
DEV void split2(float v, unsigned short& hi, unsigned short& lo){
  hi = f2bf(v); lo = f2bf(v - bf2f(hi));
}
DEV void split2h(float v, _Float16& hi, _Float16& lo){
  hi = (_Float16)v; lo = (_Float16)(v - (float)hi);
}

#define GLDS(SRC, DST) __builtin_amdgcn_global_load_lds( \
  (const __attribute__((address_space(1))) unsigned int*)(SRC), \
  (__attribute__((address_space(3))) unsigned int*)(DST), 16, 0, 0)

// ---------------------------------------------------------------------------
// fold conv1 (1x1,3->64) into conv2 (3x3,64->128)
// ---------------------------------------------------------------------------
__global__ __launch_bounds__(256) void k_fold(const float* __restrict__ w1,
    const float* __restrict__ b1, const float* __restrict__ w2,
    const float* __restrict__ b2, float* __restrict__ weff, float* __restrict__ beff)
{
  int tid = threadIdx.x;
  for (int i = tid; i < 3456; i += 256){
    int oc = i / 27, rem = i % 27, c = rem / 9, k = rem % 9;
    float s = 0.f;
    for (int m = 0; m < 64; ++m)
      s += w2[(oc*64 + m)*9 + k] * w1[m*3 + c];
    weff[i] = s;
  }
  for (int i = tid; i < 128; i += 256){
    float s = b2[i];
    for (int m = 0; m < 64; ++m){
      float t = 0.f;
      for (int k = 0; k < 9; ++k) t += w2[(i*64 + m)*9 + k];
      s += t * b1[m];
    }
    beff[i] = s;
  }
}

// ---------------------------------------------------------------------------
// conv weight prep: W9T[k][oc][ic] = bf16split(w[oc][ic][k] * bnscale[oc])
// ---------------------------------------------------------------------------
__global__ __launch_bounds__(256) void k_prepW(const float* __restrict__ w,
    const float* __restrict__ cb, const float* __restrict__ bng,
    const float* __restrict__ bnb, const float* __restrict__ bnm,
    const float* __restrict__ bnv, int useBN, int OC, int IC,
    unsigned short* __restrict__ WH, unsigned short* __restrict__ WL,
    float* __restrict__ bout)
{
  int idx = blockIdx.x*256 + threadIdx.x;
  int tot = OC*IC*9;
  if (idx < tot){
    int k = idx % 9; int t2 = idx/9; int ic = t2 % IC; int oc = t2/IC;
    float sc = useBN ? bng[oc]*rsqrtf(bnv[oc]+1e-5f) : 1.0f;
    unsigned short h,l; split2(w[idx]*sc, h, l);
    size_t o = ((size_t)k*OC + oc)*IC + ic;
    WH[o]=h; WL[o]=l;
  }
  if (idx < OC){
    float sc = useBN ? bng[idx]*rsqrtf(bnv[idx]+1e-5f) : 1.0f;
    float sh = useBN ? (bnb[idx]-bnm[idx]*sc) : 0.f;
    bout[idx] = cb[idx]*sc + sh;
  }
}

// gemm weight prep: WH/WL[oc][ic] = split(w), b = bih+bhh
__global__ __launch_bounds__(256) void k_prepWg(const float* __restrict__ w,
    const float* __restrict__ b1, const float* __restrict__ b2,
    unsigned short* __restrict__ WH, unsigned short* __restrict__ WL,
    float* __restrict__ bout)
{
  int idx = blockIdx.x*256 + threadIdx.x;
  if (idx < 1024*512){
    unsigned short h,l; split2(w[idx], h, l);
    WH[idx]=h; WL[idx]=l;
  }
  if (idx < 1024) bout[idx] = b1[idx] + b2[idx];
}

// ---------------------------------------------------------------------------
// lstm recurrent weight prep: U as SINGLE f16, pre-swizzled per-wave fragment
// order UF[dir][w(16)][kc(8)][nt(4)][lane(64)][e(8)]:
//   gate = w*64 + nt*16 + (lane&15);  k = kc*32 + (lane>>4)*8 + e
// each (kc) chunk is 4KB contiguous -> 4 GLDS stage it, fully coalesced.
// ---------------------------------------------------------------------------
__global__ __launch_bounds__(256) void k_prepU(const float* __restrict__ Uf,
    const float* __restrict__ Ub, _Float16* __restrict__ UF)
{
  int idx = blockIdx.x*256 + threadIdx.x;        // 2*262144
  if (idx < 524288){
    int e  = idx & 7;
    int l  = (idx >> 3) & 63;
    int nt = (idx >> 9) & 3;
    int kc = (idx >> 11) & 7;
    int w  = (idx >> 14) & 15;
    int d  = idx >> 18;
    int gate = w*64 + nt*16 + (l & 15);
    int k    = kc*32 + (l >> 4)*8 + e;
    const float* U = d ? Ub : Uf;
    UF[idx] = (_Float16)U[gate*256 + k];
  }
}

// ---------------------------------------------------------------------------
// fused conv2' (3x3,IC=3,OC=128) + maxpool2x2/2 -> p1 NHWC bf16 hi/lo (per half)
// ---------------------------------------------------------------------------
__global__ __launch_bounds__(256) void k_conv2pool(const float* __restrict__ x,
    const float* __restrict__ weff, const float* __restrict__ beff,
    unsigned short* __restrict__ p1H, unsigned short* __restrict__ p1L)
{
  __shared__ float wl[8*27];
  __shared__ float sm[8][4][66];
  int tx = threadIdx.x & 63, ty = threadIdx.x >> 6;
  int ocb = blockIdx.z & 15, n = blockIdx.z >> 4;   // n local 0..7
  int oc0 = ocb*8;
  if (threadIdx.x < 216) wl[threadIdx.x] = weff[oc0*27 + threadIdx.x];
  __syncthreads();
  int ow = blockIdx.x*64 + tx;
  int oh = blockIdx.y*4 + ty;
  int owc = min(ow, 509), ohc = min(oh, 61);
  const float* xp = x + ((size_t)n*3*64 + ohc)*512 + owc;
  float iv[27];
  #pragma unroll
  for (int c = 0; c < 3; ++c)
    #pragma unroll
    for (int kh = 0; kh < 3; ++kh)
      #pragma unroll
      for (int kw = 0; kw < 3; ++kw)
        iv[c*9 + kh*3 + kw] = xp[((size_t)c*64 + kh)*512 + kw];
  #pragma unroll
  for (int j = 0; j < 8; ++j){
    float s = beff[oc0 + j];
    const float* wp = &wl[j*27];
    #pragma unroll
    for (int k = 0; k < 27; ++k) s += iv[k]*wp[k];
    sm[j][ty][tx] = s;
  }
  __syncthreads();
  int pr0 = blockIdx.y*2, pc0 = blockIdx.x*32;
  for (int i = threadIdx.x; i < 512; i += 256){
    int pc = i & 31, rem = i >> 5, q = rem & 1, j = rem >> 1;
    int prow = pr0 + q, pcol = pc0 + pc;
    if (prow < 31 && pcol < 255){
      float m0 = fmaxf(sm[j][2*q  ][2*pc], sm[j][2*q  ][2*pc+1]);
      float m1 = fmaxf(sm[j][2*q+1][2*pc], sm[j][2*q+1][2*pc+1]);
      unsigned short h,l; split2(fmaxf(m0,m1), h, l);
      size_t o = (((size_t)(n*31 + prow)*255 + pcol)<<7) + oc0 + j;
      p1H[o] = h; p1L[o] = l;
    }
  }
}

// ---------------------------------------------------------------------------
// split-bf16 implicit-GEMM conv / GEMM.  C[pix][oc] = sum_{k9,ic} A*W.
// BM=128 pix (1 oh row), BN=128 oc, BK=32. 256 thr / 4 waves, mfma 16x16x32.
// ---------------------------------------------------------------------------
__global__ __launch_bounds__(256) void k_igemm(
    const unsigned short* __restrict__ inH, const unsigned short* __restrict__ inL,
    const unsigned short* __restrict__ wH,  const unsigned short* __restrict__ wL,
    const float* __restrict__ bias,
    unsigned short* __restrict__ outH, unsigned short* __restrict__ outL,
    float* __restrict__ outF,
    int IH, int IW, int IC, int OC, int OH, int OW,
    int K9, int sub, int nICc)
{
  __shared__ unsigned short lds[2][16384];  // [AH 4096][AL 4096][BH 4096][BL 4096]
  const int tid  = threadIdx.x;
  const int wv   = tid >> 6, lane = tid & 63;
  const int wr   = wv >> 1,  wc   = wv & 1;
  const int kg   = lane >> 4;
  const int ocTiles = OC >> 7;
  const int ow0 = blockIdx.x << 7;
  const int oh  = blockIdx.y;
  const int ocb = blockIdx.z % ocTiles;
  const int n   = blockIdx.z / ocTiles;
  const int oc0 = ocb << 7;

  const int sp = tid >> 2, ss = tid & 3;
  size_t aBase[2], bBase[2];
  #pragma unroll
  for (int q = 0; q < 2; ++q){
    int p = q*64 + sp;
    int opix = min(ow0 + p, OW-1);
    int sw = ss ^ ((p>>1)&3);
    aBase[q] = ((size_t)(n*IH + (oh<<sub))*IW + ((size_t)opix<<sub))*IC + sw*8;
    int o = q*64 + sp;
    int swb = ss ^ ((o>>1)&3);
    bBase[q] = (size_t)(oc0 + o)*IC + swb*8;
  }
  int aoff[4], boff[4];
  #pragma unroll
  for (int mi = 0; mi < 4; ++mi){
    int pr = wr*64 + mi*16 + (lane&15);
    aoff[mi] = pr*32 + ((kg ^ ((pr>>1)&3))*8);
  }
  #pragma unroll
  for (int nj = 0; nj < 4; ++nj){
    int orow = wc*64 + nj*16 + (lane&15);
    boff[nj] = orow*32 + ((kg ^ ((orow>>1)&3))*8);
  }

  auto STAGE = [&](int buf, int kk, int ic0){
    size_t aOff = ((size_t)((kk/3)*IW + (kk%3)))*IC + ic0;
    size_t bOff = ((size_t)kk*OC)*IC + ic0;
    unsigned short* d0 = &lds[buf][wv*512];
    #pragma unroll
    for (int q = 0; q < 2; ++q){
      GLDS(inH + aBase[q] + aOff, d0 + q*2048);
      GLDS(inL + aBase[q] + aOff, d0 + 4096  + q*2048);
      GLDS(wH  + bBase[q] + bOff, d0 + 8192  + q*2048);
      GLDS(wL  + bBase[q] + bOff, d0 + 12288 + q*2048);
    }
  };

  f32x4 acc[4][4] = {};
  const int NT = K9 * nICc;
  STAGE(0, 0, 0);
  int cur = 0;
  for (int t = 0; t < NT; ++t){
    __syncthreads();
    short8 aH[4], aL[4], bH[4], bL[4];
    #pragma unroll
    for (int mi = 0; mi < 4; ++mi){
      aH[mi] = *(const short8*)&lds[cur][aoff[mi]];
      aL[mi] = *(const short8*)&lds[cur][4096 + aoff[mi]];
    }
    #pragma unroll
    for (int nj = 0; nj < 4; ++nj){
      bH[nj] = *(const short8*)&lds[cur][8192  + boff[nj]];
      bL[nj] = *(const short8*)&lds[cur][12288 + boff[nj]];
    }
    if (t+1 < NT){
      int tn = t+1, kk = tn / nICc, icc = tn - kk*nICc;
      STAGE(cur^1, kk, icc*32);
    }
    #pragma unroll
    for (int mi = 0; mi < 4; ++mi)
      #pragma unroll
      for (int nj = 0; nj < 4; ++nj){
        acc[mi][nj] = __builtin_amdgcn_mfma_f32_16x16x32_bf16(aH[mi], bH[nj], acc[mi][nj],0,0,0);
        acc[mi][nj] = __builtin_amdgcn_mfma_f32_16x16x32_bf16(aL[mi], bH[nj], acc[mi][nj],0,0,0);
        acc[mi][nj] = __builtin_amdgcn_mfma_f32_16x16x32_bf16(aH[mi], bL[nj], acc[mi][nj],0,0,0);
      }
    cur ^= 1;
  }

  const int ocL = oc0 + wc*64 + (lane&15);
  const int rb  = wr*64 + ((lane>>4)<<2);
  #pragma unroll
  for (int nj = 0; nj < 4; ++nj){
    int oc = ocL + nj*16;
    float bs = bias[oc];
    #pragma unroll
    for (int mi = 0; mi < 4; ++mi)
      #pragma unroll
      for (int j = 0; j < 4; ++j){
        int pix = ow0 + rb + mi*16 + j;
        if (pix < OW){
          size_t oi = ((size_t)(n*OH + oh)*OW + pix)*OC + oc;
          float v = acc[mi][nj][j] + bs;
          if (outF) outF[oi] = v;
          else { unsigned short h,l; split2(v,h,l); outH[oi]=h; outL[oi]=l; }
        }
      }
  }
}

// ---------------------------------------------------------------------------
// maxpool 2x2/1 on NHWC bf16 hi/lo, per half: (8,27,251,256)->(8,26,250,256)
// ---------------------------------------------------------------------------
__global__ __launch_bounds__(256) void k_pool2(const unsigned short* __restrict__ yH,
    const unsigned short* __restrict__ yL,
    unsigned short* __restrict__ pH, unsigned short* __restrict__ pL)
{
  int idx = blockIdx.x*256 + threadIdx.x;       // over 8*26*250*32
  if (idx >= 1664000) return;
  int g = idx & 31; int t2 = idx >> 5;
  int pw = t2 % 250; t2 /= 250; int ph = t2 % 26; int n = t2 / 26;
  size_t base = (((size_t)(n*27 + ph)*251 + pw)<<8) + g*8;
  float v[8];
  #pragma unroll
  for (int e = 0; e < 8; ++e) v[e] = -3.4e38f;
  #pragma unroll
  for (int r = 0; r < 2; ++r)
    #pragma unroll
    for (int c = 0; c < 2; ++c){
      size_t o = base + ((size_t)(r*251 + c)<<8);
      ushort8 hv = *(const ushort8*)&yH[o];
      ushort8 lv = *(const ushort8*)&yL[o];
      #pragma unroll
      for (int e = 0; e < 8; ++e)
        v[e] = fmaxf(v[e], bf2f(hv[e]) + bf2f(lv[e]));
    }
  ushort8 oh8, ol8;
  #pragma unroll
  for (int e = 0; e < 8; ++e){ unsigned short h,l; split2(v[e],h,l); oh8[e]=h; ol8[e]=l; }
  size_t ob = (((size_t)(n*26 + ph)*250 + pw)<<8) + g*8;
  *(ushort8*)&pH[ob] = oh8;
  *(ushort8*)&pL[ob] = ol8;
}

// ---------------------------------------------------------------------------
// MFMA bidirectional LSTM, GLDS-streamed U.
// 20 blocks = 10 row-blocks x 2 dirs; 1024 thr / 16 waves; 16 sequences/block.
// Per step: gates(16x1024) = h(16x256)@U^T via mfma_f32_16x16x32_f16.
// h split f16 hi/lo (2 products); U single f16 streamed from L2 via
// wave-private double-buffered global_load_lds with counted vmcnt (never 0
// mid-loop).  gl (fp32 gate exchange) aliases the staging region (dead after
// barrier1).  3 barriers/step.
// ---------------------------------------------------------------------------
__global__ __launch_bounds__(1024, 4) void k_lstm(const float* __restrict__ pre,
    const _Float16* __restrict__ UF, float* __restrict__ out)
{
  // [0,131072): staging 16 waves x 8KB (2 bufs x 4KB); gl aliased [0,65792)
  // [131072,139264): hAh   [139264,147456): hAl
  __shared__ __align__(16) unsigned char smem[147456];
  const int t   = threadIdx.x;
  const int b   = blockIdx.x;
  const int dir = b & 1, rbk = b >> 1;
  const int r0  = rbk * 16;
  const int w   = t >> 6, l = t & 63;
  const int g0   = w * 64;
  const int colL = l & 15, kgL = l >> 4;
  const int lam  = (t >> 1) & 63;
  const int grow = lam & 15;
  const int kcG  = t >> 7;
  const int half = t & 1;
  const int j0   = kcG*32 + (lam >> 4)*8 + half*4;

  float*    gl   = (float*)smem;
  _Float16* stgW = (_Float16*)smem + (size_t)w*4096;       // 2 bufs x 2048 f16
  _Float16* hAh  = (_Float16*)(smem + 131072);
  _Float16* hAl  = (_Float16*)(smem + 139264);

  const float* preD = pre + (size_t)dir*19988480ull
                    + ((size_t)(r0 + grow)*122)*1024 + j0;
  float* outD = out + ((size_t)(r0 + grow)*122)*512 + dir*256 + j0;
  const _Float16* srcL = UF + (size_t)dir*262144 + (size_t)w*16384 + l*8;
  const int hIdx = kcG*512 + lam*8 + half*4;

  // zero h fragments: 1024 thr x 4 f16 x 2 arrays = full cover
  { uint2 z{0,0}; *(uint2*)&hAh[t*4] = z; *(uint2*)&hAl[t*4] = z; }
  __syncthreads();

  float c0 = 0.f, c1 = 0.f, c2 = 0.f, c3 = 0.f;

#define STG(KC_, B_) { \
    GLDS(srcL + (KC_)*2048 +    0, stgW + (B_)*2048 +    0); \
    GLDS(srcL + (KC_)*2048 +  512, stgW + (B_)*2048 +  512); \
    GLDS(srcL + (KC_)*2048 + 1024, stgW + (B_)*2048 + 1024); \
    GLDS(srcL + (KC_)*2048 + 1536, stgW + (B_)*2048 + 1536); }

  for (int s = 0; s < 122; ++s){
    const int tt = dir ? (121 - s) : s;
    const float* pp = preD + (size_t)tt*1024;
    float4 pg0 = *(const float4*)(pp);
    float4 pg1 = *(const float4*)(pp + 256);
    float4 pg2 = *(const float4*)(pp + 512);
    float4 pg3 = *(const float4*)(pp + 768);

    STG(0, 0); STG(1, 1);

    f32x4 acc0 = {}, acc1 = {}, acc2 = {}, acc3 = {};
    #pragma unroll
    for (int kc = 0; kc < 8; ++kc){
      const int bb = kc & 1;
      if (kc < 7) { asm volatile("s_waitcnt vmcnt(4)" ::: "memory"); }
      else        { asm volatile("s_waitcnt vmcnt(0)" ::: "memory"); }
      __builtin_amdgcn_sched_barrier(0);
      f16x8 Ah = *(const f16x8*)&hAh[kc*512 + l*8];
      f16x8 Al = *(const f16x8*)&hAl[kc*512 + l*8];
      f16x8 B0 = *(const f16x8*)&stgW[bb*2048 +        l*8];
      f16x8 B1 = *(const f16x8*)&stgW[bb*2048 +  512 + l*8];
      f16x8 B2 = *(const f16x8*)&stgW[bb*2048 + 1024 + l*8];
      f16x8 B3 = *(const f16x8*)&stgW[bb*2048 + 1536 + l*8];
      asm volatile("s_waitcnt lgkmcnt(0)" ::: "memory");   // drain reads before restage
      __builtin_amdgcn_sched_barrier(0);
      if (kc < 6) STG(kc+2, bb);
      acc0 = __builtin_amdgcn_mfma_f32_16x16x32_f16(Ah, B0, acc0, 0,0,0);
      acc0 = __builtin_amdgcn_mfma_f32_16x16x32_f16(Al, B0, acc0, 0,0,0);
      acc1 = __builtin_amdgcn_mfma_f32_16x16x32_f16(Ah, B1, acc1, 0,0,0);
      acc1 = __builtin_amdgcn_mfma_f32_16x16x32_f16(Al, B1, acc1, 0,0,0);
      acc2 = __builtin_amdgcn_mfma_f32_16x16x32_f16(Ah, B2, acc2, 0,0,0);
      acc2 = __builtin_amdgcn_mfma_f32_16x16x32_f16(Al, B2, acc2, 0,0,0);
      acc3 = __builtin_amdgcn_mfma_f32_16x16x32_f16(Ah, B3, acc3, 0,0,0);
      acc3 = __builtin_amdgcn_mfma_f32_16x16x32_f16(Al, B3, acc3, 0,0,0);
    }
    __syncthreads();                       // barrier1: staging region now dead
    {
      const int rbase = kgL*4;
      #pragma unroll
      for (int q = 0; q < 4; ++q){
        gl[(rbase+q)*1028 + g0 +  0 + colL] = acc0[q];
        gl[(rbase+q)*1028 + g0 + 16 + colL] = acc1[q];
        gl[(rbase+q)*1028 + g0 + 32 + colL] = acc2[q];
        gl[(rbase+q)*1028 + g0 + 48 + colL] = acc3[q];
      }
    }
    __syncthreads();                       // barrier2: gl ready

    float4 gi = *(const float4*)&gl[grow*1028 +       j0];
    float4 gf = *(const float4*)&gl[grow*1028 + 256 + j0];
    float4 gg = *(const float4*)&gl[grow*1028 + 512 + j0];
    float4 go = *(const float4*)&gl[grow*1028 + 768 + j0];
    float h0,h1,h2,h3;
    {
      float i_ = sigm(gi.x + pg0.x), f_ = sigm(gf.x + pg1.x);
      float g_ = tanhx(gg.x + pg2.x), o_ = sigm(go.x + pg3.x);
      c0 = f_*c0 + i_*g_;  h0 = o_*tanhx(c0);
    }{
      float i_ = sigm(gi.y + pg0.y), f_ = sigm(gf.y + pg1.y);
      float g_ = tanhx(gg.y + pg2.y), o_ = sigm(go.y + pg3.y);
      c1 = f_*c1 + i_*g_;  h1 = o_*tanhx(c1);
    }{
      float i_ = sigm(gi.z + pg0.z), f_ = sigm(gf.z + pg1.z);
      float g_ = tanhx(gg.z + pg2.z), o_ = sigm(go.z + pg3.z);
      c2 = f_*c2 + i_*g_;  h2 = o_*tanhx(c2);
    }{
      float i_ = sigm(gi.w + pg0.w), f_ = sigm(gf.w + pg1.w);
      float g_ = tanhx(gg.w + pg2.w), o_ = sigm(go.w + pg3.w);
      c3 = f_*c3 + i_*g_;  h3 = o_*tanhx(c3);
    }
    *(float4*)(outD + (size_t)tt*512) = make_float4(h0,h1,h2,h3);
    _Float16 hh[4], hl[4];
    split2h(h0, hh[0], hl[0]); split2h(h1, hh[1], hl[1]);
    split2h(h2, hh[2], hl[2]); split2h(h3, hh[3], hl[3]);
    *(uint2*)&hAh[hIdx] = *(uint2*)hh;
    *(uint2*)&hAl[hIdx] = *(uint2*)hl;
    __syncthreads();                       // barrier3: hA ready, gl/staging free
  }
#undef STG
}

// ---------------------------------------------------------------------------
// host.  ws layout (float units), peak ~51.44M floats = 206 MB:
//  pre @0 (39.98M) | conv arena (per batch-half, reused): y3@0, y4@15.1M,
//  p1@29.0M, p2@0, p3@15.1M | rowsLo @40.0M | UF@45.1M | W @45.65M+
// ---------------------------------------------------------------------------
extern "C" void kernel_launch(void* const* d_in, const int* in_sizes, int n_in,
                              void* d_out, int out_size, void* d_ws, size_t ws_size,
                              hipStream_t stream)
{
  const float* x    = (const float*)d_in[0];
  const float* c1w  = (const float*)d_in[1];
  const float* c1b  = (const float*)d_in[2];
  const float* c2w  = (const float*)d_in[3];
  const float* c2b  = (const float*)d_in[4];
  const float* c3w  = (const float*)d_in[5];
  const float* c3b  = (const float*)d_in[6];
  const float* bn1g = (const float*)d_in[7];
  const float* bn1b = (const float*)d_in[8];
  const float* bn1m = (const float*)d_in[9];
  const float* bn1v = (const float*)d_in[10];
  const float* c4w  = (const float*)d_in[11];
  const float* c4b  = (const float*)d_in[12];
  const float* c5w  = (const float*)d_in[13];
  const float* c5b  = (const float*)d_in[14];
  const float* bn2g = (const float*)d_in[15];
  const float* bn2b = (const float*)d_in[16];
  const float* bn2m = (const float*)d_in[17];
  const float* bn2v = (const float*)d_in[18];
  const float* c6w  = (const float*)d_in[19];
  const float* c6b  = (const float*)d_in[20];
  const float* bn3g = (const float*)d_in[21];
  const float* bn3b = (const float*)d_in[22];
  const float* bn3m = (const float*)d_in[23];
  const float* bn3v = (const float*)d_in[24];
  const float* wihf = (const float*)d_in[25];
  const float* whhf = (const float*)d_in[26];
  const float* bihf = (const float*)d_in[27];
  const float* bhhf = (const float*)d_in[28];
  const float* wihb = (const float*)d_in[29];
  const float* whhb = (const float*)d_in[30];
  const float* bihb = (const float*)d_in[31];
  const float* bhhb = (const float*)d_in[32];

  float* ws = (float*)d_ws;
  typedef unsigned short u16;

  float* pre  = ws;                                   // 39,976,960 f
  u16*   y3H  = (u16*)(ws);            u16* y3L = y3H + 15026176ull;
  u16*   y4H  = (u16*)(ws + 15100000ull); u16* y4L = y4H + 13879296ull;
  u16*   p1H  = (u16*)(ws + 29000000ull); u16* p1L = p1H + 8094720ull;
  u16*   p2H  = (u16*)(ws);            u16* p2L = p2H + 13312000ull;
  u16*   p3H  = (u16*)(ws + 15100000ull); u16* p3L = p3H + 6094848ull;
  u16*   rowsL= (u16*)(ws + 40000000ull);             // 9,994,240 u
  _Float16* UFd = (_Float16*)(ws + 45100000ull);      // 524,288 f16 (swizzled)
  u16*   W3H  = (u16*)(ws + 45650000ull); u16* W3L = (u16*)(ws + 45800000ull);
  u16*   W4H  = (u16*)(ws + 45950000ull); u16* W4L = (u16*)(ws + 46250000ull);
  u16*   W5H  = (u16*)(ws + 46550000ull); u16* W5L = (u16*)(ws + 47150000ull);
  u16*   W6H  = (u16*)(ws + 47750000ull); u16* W6L = (u16*)(ws + 48950000ull);
  u16*   WgfH = (u16*)(ws + 50150000ull); u16* WgfL = (u16*)(ws + 50450000ull);
  u16*   WgbH = (u16*)(ws + 50750000ull); u16* WgbL = (u16*)(ws + 51050000ull);
  float* b3   = ws + 51350000ull;
  float* b4   = ws + 51360000ull;
  float* b5   = ws + 51370000ull;
  float* b6   = ws + 51380000ull;
  float* bgf  = ws + 51390000ull;
  float* bgb  = ws + 51400000ull;
  float* weff = ws + 51420000ull;
  float* beff = ws + 51430000ull;
  u16*   rowsH = (u16*)d_out;                         // 9,994,240 u (in d_out)
  float* outF  = (float*)d_out;

  // ---- weight preparation ----
  k_fold<<<1, 256, 0, stream>>>(c1w, c1b, c2w, c2b, weff, beff);
  k_prepW<<<1152, 256, 0, stream>>>(c3w, c3b, bn1g,bn1b,bn1m,bn1v, 1, 256,128, W3H,W3L, b3);
  k_prepW<<<2304, 256, 0, stream>>>(c4w, c4b, nullptr,nullptr,nullptr,nullptr, 0, 256,256, W4H,W4L, b4);
  k_prepW<<<4608, 256, 0, stream>>>(c5w, c5b, bn2g,bn2b,bn2m,bn2v, 1, 512,256, W5H,W5L, b5);
  k_prepW<<<9216, 256, 0, stream>>>(c6w, c6b, bn3g,bn3b,bn3m,bn3v, 1, 512,512, W6H,W6L, b6);
  k_prepWg<<<2048, 256, 0, stream>>>(wihf, bihf, bhhf, WgfH, WgfL, bgf);
  k_prepWg<<<2048, 256, 0, stream>>>(wihb, bihb, bhhb, WgbH, WgbL, bgb);
  k_prepU<<<2048, 256, 0, stream>>>(whhf, whhb, UFd);

  // ---- conv chain, two batch-halves of 8 images ----
  for (int hb = 0; hb < 2; ++hb){
    int nB = hb*8;
    const float* xh = x + (size_t)nB*98304ull;
    k_conv2pool<<<dim3(8,16,128), 256, 0, stream>>>(xh, weff, beff, p1H, p1L);
    k_igemm<<<dim3(2,29,16), 256, 0, stream>>>(p1H,p1L, W3H,W3L, b3,
        y3H,y3L, nullptr, 31,255,128,256,29,253, 9,0,4);
    k_igemm<<<dim3(2,27,16), 256, 0, stream>>>(y3H,y3L, W4H,W4L, b4,
        y4H,y4L, nullptr, 29,253,256,256,27,251, 9,0,8);
    k_pool2<<<6500, 256, 0, stream>>>(y4H,y4L, p2H,p2L);
    k_igemm<<<dim3(1,12,32), 256, 0, stream>>>(p2H,p2L, W5H,W5L, b5,
        p3H,p3L, nullptr, 26,250,256,512,12,124, 9,1,8);
    k_igemm<<<dim3(1,10,32), 256, 0, stream>>>(p3H,p3L, W6H,W6L, b6,
        rowsH + (size_t)nB*624640ull, rowsL + (size_t)nB*624640ull, nullptr,
        12,124,512,512,10,122, 9,0,16);
  }

  // ---- input projection GEMMs: rows(19520x512) @ W^T(512x1024) -> pre fp32 ----
  k_igemm<<<dim3(153,1,8), 256, 0, stream>>>(rowsH,rowsL, WgfH,WgfL, bgf,
      nullptr,nullptr, pre, 1,19520,512,1024,1,19520, 1,0,16);
  k_igemm<<<dim3(153,1,8), 256, 0, stream>>>(rowsH,rowsL, WgbH,WgbL, bgb,
      nullptr,nullptr, pre + 19988480ull, 1,19520,512,1024,1,19520, 1,0,16);

  // ---- recurrence (MFMA f16, GLDS-streamed U) ----
  k_lstm<<<20, 1024, 0, stream>>>(pre, UFd, outF);
}

// Round 10
// 2704.615 us; speedup vs baseline: 1.8996x; 1.1989x over previous
//
#include <hip/hip_runtime.h>
#include <cmath>

#define DEV __device__ __forceinline__

typedef __attribute__((ext_vector_type(8))) short  short8;
typedef __attribute__((ext_vector_type(8))) unsigned short ushort8;
typedef __attribute__((ext_vector_type(4))) float  f32x4;
typedef __attribute__((ext_vector_type(2))) _Float16 f16x2;

DEV float sigm(float x){ return 1.0f/(1.0f + __expf(-x)); }
DEV float tanhx(float x){
  x = fminf(fmaxf(x, -15.0f), 15.0f);
  float e = __expf(2.0f*x);
  return (e - 1.0f)/(e + 1.0f);
}
DEV unsigned short f2bf(float f){
  unsigned u = __float_as_uint(f);
  return (unsigned short)((u + 0x7fffu + ((u>>16)&1u)) >> 16);
}
DEV float bf2f(unsigned short h){ return __uint_as_float(((unsigned)h)<<16); }
DEV void split2(float v, unsigned short& hi, unsigned short& lo){
  hi = f2bf(v); lo = f2bf(v - bf2f(hi));
}

#define GLDS(SRC, DST) __builtin_amdgcn_global_load_lds( \
  (const __attribute__((address_space(1))) unsigned int*)(SRC), \
  (__attribute__((address_space(3))) unsigned int*)(DST), 16, 0, 0)

// ---------------------------------------------------------------------------
// fold conv1 (1x1,3->64) into conv2 (3x3,64->128)
// ---------------------------------------------------------------------------
__global__ __launch_bounds__(256) void k_fold(const float* __restrict__ w1,
    const float* __restrict__ b1, const float* __restrict__ w2,
    const float* __restrict__ b2, float* __restrict__ weff, float* __restrict__ beff)
{
  int tid = threadIdx.x;
  for (int i = tid; i < 3456; i += 256){
    int oc = i / 27, rem = i % 27, c = rem / 9, k = rem % 9;
    float s = 0.f;
    for (int m = 0; m < 64; ++m)
      s += w2[(oc*64 + m)*9 + k] * w1[m*3 + c];
    weff[i] = s;
  }
  for (int i = tid; i < 128; i += 256){
    float s = b2[i];
    for (int m = 0; m < 64; ++m){
      float t = 0.f;
      for (int k = 0; k < 9; ++k) t += w2[(i*64 + m)*9 + k];
      s += t * b1[m];
    }
    beff[i] = s;
  }
}

// ---------------------------------------------------------------------------
// conv weight prep: W9T[k][oc][ic] = bf16split(w[oc][ic][k] * bnscale[oc])
// ---------------------------------------------------------------------------
__global__ __launch_bounds__(256) void k_prepW(const float* __restrict__ w,
    const float* __restrict__ cb, const float* __restrict__ bng,
    const float* __restrict__ bnb, const float* __restrict__ bnm,
    const float* __restrict__ bnv, int useBN, int OC, int IC,
    unsigned short* __restrict__ WH, unsigned short* __restrict__ WL,
    float* __restrict__ bout)
{
  int idx = blockIdx.x*256 + threadIdx.x;
  int tot = OC*IC*9;
  if (idx < tot){
    int k = idx % 9; int t2 = idx/9; int ic = t2 % IC; int oc = t2/IC;
    float sc = useBN ? bng[oc]*rsqrtf(bnv[oc]+1e-5f) : 1.0f;
    unsigned short h,l; split2(w[idx]*sc, h, l);
    size_t o = ((size_t)k*OC + oc)*IC + ic;
    WH[o]=h; WL[o]=l;
  }
  if (idx < OC){
    float sc = useBN ? bng[idx]*rsqrtf(bnv[idx]+1e-5f) : 1.0f;
    float sh = useBN ? (bnb[idx]-bnm[idx]*sc) : 0.f;
    bout[idx] = cb[idx]*sc + sh;
  }
}

// gemm weight prep: WH/WL[oc][ic] = split(w), b = bih+bhh
__global__ __launch_bounds__(256) void k_prepWg(const float* __restrict__ w,
    const float* __restrict__ b1, const float* __restrict__ b2,
    unsigned short* __restrict__ WH, unsigned short* __restrict__ WL,
    float* __restrict__ bout)
{
  int idx = blockIdx.x*256 + threadIdx.x;
  if (idx < 1024*512){
    unsigned short h,l; split2(w[idx], h, l);
    WH[idx]=h; WL[idx]=l;
  }
  if (idx < 1024) bout[idx] = b1[idx] + b2[idx];
}

// ---------------------------------------------------------------------------
// lstm recurrent weight prep: U packed f16x2 by k-pairs, transposed:
//   UP[dir][k2][g] = (f16(U[g][2k2]), f16(U[g][2k2+1]))  as one uint.
// consecutive g -> coalesced 4B/lane loads in k_lstm.
// ---------------------------------------------------------------------------
__global__ __launch_bounds__(256) void k_prepU(const float* __restrict__ Uf,
    const float* __restrict__ Ub, unsigned* __restrict__ UP)
{
  int idx = blockIdx.x*256 + threadIdx.x;        // 262144 total
  if (idx < 262144){
    int d = idx >> 17; int rem = idx & 131071;
    int k2 = rem >> 10, g = rem & 1023;
    const float* U = d ? Ub : Uf;
    _Float16 a = (_Float16)U[g*256 + 2*k2];
    _Float16 b = (_Float16)U[g*256 + 2*k2 + 1];
    unsigned ua = (unsigned)__builtin_bit_cast(unsigned short, a);
    unsigned ub = (unsigned)__builtin_bit_cast(unsigned short, b);
    UP[idx] = ua | (ub << 16);
  }
}

// ---------------------------------------------------------------------------
// fused conv2' (3x3,IC=3,OC=128) + maxpool2x2/2 -> p1 NHWC bf16 hi/lo (per half)
// ---------------------------------------------------------------------------
__global__ __launch_bounds__(256) void k_conv2pool(const float* __restrict__ x,
    const float* __restrict__ weff, const float* __restrict__ beff,
    unsigned short* __restrict__ p1H, unsigned short* __restrict__ p1L)
{
  __shared__ float wl[8*27];
  __shared__ float sm[8][4][66];
  int tx = threadIdx.x & 63, ty = threadIdx.x >> 6;
  int ocb = blockIdx.z & 15, n = blockIdx.z >> 4;   // n local 0..7
  int oc0 = ocb*8;
  if (threadIdx.x < 216) wl[threadIdx.x] = weff[oc0*27 + threadIdx.x];
  __syncthreads();
  int ow = blockIdx.x*64 + tx;
  int oh = blockIdx.y*4 + ty;
  int owc = min(ow, 509), ohc = min(oh, 61);
  const float* xp = x + ((size_t)n*3*64 + ohc)*512 + owc;
  float iv[27];
  #pragma unroll
  for (int c = 0; c < 3; ++c)
    #pragma unroll
    for (int kh = 0; kh < 3; ++kh)
      #pragma unroll
      for (int kw = 0; kw < 3; ++kw)
        iv[c*9 + kh*3 + kw] = xp[((size_t)c*64 + kh)*512 + kw];
  #pragma unroll
  for (int j = 0; j < 8; ++j){
    float s = beff[oc0 + j];
    const float* wp = &wl[j*27];
    #pragma unroll
    for (int k = 0; k < 27; ++k) s += iv[k]*wp[k];
    sm[j][ty][tx] = s;
  }
  __syncthreads();
  int pr0 = blockIdx.y*2, pc0 = blockIdx.x*32;
  for (int i = threadIdx.x; i < 512; i += 256){
    int pc = i & 31, rem = i >> 5, q = rem & 1, j = rem >> 1;
    int prow = pr0 + q, pcol = pc0 + pc;
    if (prow < 31 && pcol < 255){
      float m0 = fmaxf(sm[j][2*q  ][2*pc], sm[j][2*q  ][2*pc+1]);
      float m1 = fmaxf(sm[j][2*q+1][2*pc], sm[j][2*q+1][2*pc+1]);
      unsigned short h,l; split2(fmaxf(m0,m1), h, l);
      size_t o = (((size_t)(n*31 + prow)*255 + pcol)<<7) + oc0 + j;
      p1H[o] = h; p1L[o] = l;
    }
  }
}

// ---------------------------------------------------------------------------
// split-bf16 implicit-GEMM conv / GEMM.  C[pix][oc] = sum_{k9,ic} A*W.
// BM=128 pix (1 oh row), BN=128 oc, BK=32. 256 thr / 4 waves, mfma 16x16x32.
// ---------------------------------------------------------------------------
__global__ __launch_bounds__(256) void k_igemm(
    const unsigned short* __restrict__ inH, const unsigned short* __restrict__ inL,
    const unsigned short* __restrict__ wH,  const unsigned short* __restrict__ wL,
    const float* __restrict__ bias,
    unsigned short* __restrict__ outH, unsigned short* __restrict__ outL,
    float* __restrict__ outF,
    int IH, int IW, int IC, int OC, int OH, int OW,
    int K9, int sub, int nICc)
{
  __shared__ unsigned short lds[2][16384];  // [AH 4096][AL 4096][BH 4096][BL 4096]
  const int tid  = threadIdx.x;
  const int wv   = tid >> 6, lane = tid & 63;
  const int wr   = wv >> 1,  wc   = wv & 1;
  const int kg   = lane >> 4;
  const int ocTiles = OC >> 7;
  const int ow0 = blockIdx.x << 7;
  const int oh  = blockIdx.y;
  const int ocb = blockIdx.z % ocTiles;
  const int n   = blockIdx.z / ocTiles;
  const int oc0 = ocb << 7;

  const int sp = tid >> 2, ss = tid & 3;
  size_t aBase[2], bBase[2];
  #pragma unroll
  for (int q = 0; q < 2; ++q){
    int p = q*64 + sp;
    int opix = min(ow0 + p, OW-1);
    int sw = ss ^ ((p>>1)&3);
    aBase[q] = ((size_t)(n*IH + (oh<<sub))*IW + ((size_t)opix<<sub))*IC + sw*8;
    int o = q*64 + sp;
    int swb = ss ^ ((o>>1)&3);
    bBase[q] = (size_t)(oc0 + o)*IC + swb*8;
  }
  int aoff[4], boff[4];
  #pragma unroll
  for (int mi = 0; mi < 4; ++mi){
    int pr = wr*64 + mi*16 + (lane&15);
    aoff[mi] = pr*32 + ((kg ^ ((pr>>1)&3))*8);
  }
  #pragma unroll
  for (int nj = 0; nj < 4; ++nj){
    int orow = wc*64 + nj*16 + (lane&15);
    boff[nj] = orow*32 + ((kg ^ ((orow>>1)&3))*8);
  }

  auto STAGE = [&](int buf, int kk, int ic0){
    size_t aOff = ((size_t)((kk/3)*IW + (kk%3)))*IC + ic0;
    size_t bOff = ((size_t)kk*OC)*IC + ic0;
    unsigned short* d0 = &lds[buf][wv*512];
    #pragma unroll
    for (int q = 0; q < 2; ++q){
      GLDS(inH + aBase[q] + aOff, d0 + q*2048);
      GLDS(inL + aBase[q] + aOff, d0 + 4096  + q*2048);
      GLDS(wH  + bBase[q] + bOff, d0 + 8192  + q*2048);
      GLDS(wL  + bBase[q] + bOff, d0 + 12288 + q*2048);
    }
  };

  f32x4 acc[4][4] = {};
  const int NT = K9 * nICc;
  STAGE(0, 0, 0);
  int cur = 0;
  for (int t = 0; t < NT; ++t){
    __syncthreads();
    short8 aH[4], aL[4], bH[4], bL[4];
    #pragma unroll
    for (int mi = 0; mi < 4; ++mi){
      aH[mi] = *(const short8*)&lds[cur][aoff[mi]];
      aL[mi] = *(const short8*)&lds[cur][4096 + aoff[mi]];
    }
    #pragma unroll
    for (int nj = 0; nj < 4; ++nj){
      bH[nj] = *(const short8*)&lds[cur][8192  + boff[nj]];
      bL[nj] = *(const short8*)&lds[cur][12288 + boff[nj]];
    }
    if (t+1 < NT){
      int tn = t+1, kk = tn / nICc, icc = tn - kk*nICc;
      STAGE(cur^1, kk, icc*32);
    }
    #pragma unroll
    for (int mi = 0; mi < 4; ++mi)
      #pragma unroll
      for (int nj = 0; nj < 4; ++nj){
        acc[mi][nj] = __builtin_amdgcn_mfma_f32_16x16x32_bf16(aH[mi], bH[nj], acc[mi][nj],0,0,0);
        acc[mi][nj] = __builtin_amdgcn_mfma_f32_16x16x32_bf16(aL[mi], bH[nj], acc[mi][nj],0,0,0);
        acc[mi][nj] = __builtin_amdgcn_mfma_f32_16x16x32_bf16(aH[mi], bL[nj], acc[mi][nj],0,0,0);
      }
    cur ^= 1;
  }

  const int ocL = oc0 + wc*64 + (lane&15);
  const int rb  = wr*64 + ((lane>>4)<<2);
  #pragma unroll
  for (int nj = 0; nj < 4; ++nj){
    int oc = ocL + nj*16;
    float bs = bias[oc];
    #pragma unroll
    for (int mi = 0; mi < 4; ++mi)
      #pragma unroll
      for (int j = 0; j < 4; ++j){
        int pix = ow0 + rb + mi*16 + j;
        if (pix < OW){
          size_t oi = ((size_t)(n*OH + oh)*OW + pix)*OC + oc;
          float v = acc[mi][nj][j] + bs;
          if (outF) outF[oi] = v;
          else { unsigned short h,l; split2(v,h,l); outH[oi]=h; outL[oi]=l; }
        }
      }
  }
}

// ---------------------------------------------------------------------------
// maxpool 2x2/1 on NHWC bf16 hi/lo, per half: (8,27,251,256)->(8,26,250,256)
// ---------------------------------------------------------------------------
__global__ __launch_bounds__(256) void k_pool2(const unsigned short* __restrict__ yH,
    const unsigned short* __restrict__ yL,
    unsigned short* __restrict__ pH, unsigned short* __restrict__ pL)
{
  int idx = blockIdx.x*256 + threadIdx.x;       // over 8*26*250*32
  if (idx >= 1664000) return;
  int g = idx & 31; int t2 = idx >> 5;
  int pw = t2 % 250; t2 /= 250; int ph = t2 % 26; int n = t2 / 26;
  size_t base = (((size_t)(n*27 + ph)*251 + pw)<<8) + g*8;
  float v[8];
  #pragma unroll
  for (int e = 0; e < 8; ++e) v[e] = -3.4e38f;
  #pragma unroll
  for (int r = 0; r < 2; ++r)
    #pragma unroll
    for (int c = 0; c < 2; ++c){
      size_t o = base + ((size_t)(r*251 + c)<<8);
      ushort8 hv = *(const ushort8*)&yH[o];
      ushort8 lv = *(const ushort8*)&yL[o];
      #pragma unroll
      for (int e = 0; e < 8; ++e)
        v[e] = fmaxf(v[e], bf2f(hv[e]) + bf2f(lv[e]));
    }
  ushort8 oh8, ol8;
  #pragma unroll
  for (int e = 0; e < 8; ++e){ unsigned short h,l; split2(v[e],h,l); oh8[e]=h; ol8[e]=l; }
  size_t ob = (((size_t)(n*26 + ph)*250 + pw)<<8) + g*8;
  *(ushort8*)&pH[ob] = oh8;
  *(ushort8*)&pL[ob] = ol8;
}

// ---------------------------------------------------------------------------
// bidirectional LSTM recurrence (proven round-4 scalar structure, f16x2 U).
// 160 blocks = 80 row-pairs x 2 dirs; 1024 threads; thread g owns gate g
// for BOTH rows of its pair.  Per 2 k's: 1 coalesced 4B U-load (f16x2) +
// 1 float4 LDS read (h of both rows) + 2 cvt + 4 FMA.  Gates via 8KB LDS
// roundtrip; c-state in registers of threads < 512.  2 barriers/step.
// ---------------------------------------------------------------------------
__global__ __launch_bounds__(1024) void k_lstm(const float* __restrict__ pre,
    const unsigned* __restrict__ UP, float* __restrict__ out)
{
  int b = blockIdx.x;
  int dir = (b >= 80) ? 1 : 0;
  int r0 = (b - dir*80)*2;
  int g = threadIdx.x;                     // gate dim 0..1023
  const unsigned* Ut = UP + (size_t)dir*131072 + g;
  const float* preD = pre + (size_t)dir*19988480ull;
  __shared__ __align__(16) float2 hsh[256];   // h[k] row0 (.x) / row1 (.y)
  __shared__ float gl[2][1024];
  if (g < 256) hsh[g] = make_float2(0.f, 0.f);
  __syncthreads();
  float c = 0.f;                           // c-state (threads < 512)
  const int row = g >> 8, j = g & 255;

  const float* p0 = preD + ((size_t)r0*122)*1024 + g;
  for (int s = 0; s < 122; ++s){
    int t = dir ? (121 - s) : s;
    float a0 = p0[(size_t)t*1024];
    float a1 = p0[(size_t)t*1024 + 124928];   // row r0+1 (= +122*1024)
    const unsigned* up = Ut;
    #pragma unroll 8
    for (int k2 = 0; k2 < 128; ++k2){
      float4 hv = *(const float4*)&hsh[2*k2];  // h0[2k2],h1[2k2],h0[2k2+1],h1[2k2+1]
      unsigned uw = *up;
      f16x2 uv = __builtin_bit_cast(f16x2, uw);
      float u0 = (float)uv[0], u1 = (float)uv[1];
      a0 = fmaf(hv.x, u0, a0);
      a1 = fmaf(hv.y, u0, a1);
      a0 = fmaf(hv.z, u1, a0);
      a1 = fmaf(hv.w, u1, a1);
      up += 1024;
    }
    gl[0][g] = a0; gl[1][g] = a1;
    __syncthreads();
    if (g < 512){
      float i_ = sigm(gl[row][j]);
      float f_ = sigm(gl[row][256+j]);
      float g_ = tanhx(gl[row][512+j]);
      float o_ = sigm(gl[row][768+j]);
      c = f_*c + i_*g_;
      float nh = o_*tanhx(c);
      if (row == 0) hsh[j].x = nh; else hsh[j].y = nh;
      out[((size_t)(r0+row)*122 + t)*512 + dir*256 + j] = nh;
    }
    __syncthreads();
  }
}

// ---------------------------------------------------------------------------
// host.  ws layout (float units), peak ~51.44M floats = 206 MB:
//  pre @0 (39.98M) | conv arena (per batch-half, reused): y3@0, y4@15.1M,
//  p1@29.0M, p2@0, p3@15.1M | rowsLo @40.0M | UP@45.1M | W @45.65M+
// ---------------------------------------------------------------------------
extern "C" void kernel_launch(void* const* d_in, const int* in_sizes, int n_in,
                              void* d_out, int out_size, void* d_ws, size_t ws_size,
                              hipStream_t stream)
{
  const float* x    = (const float*)d_in[0];
  const float* c1w  = (const float*)d_in[1];
  const float* c1b  = (const float*)d_in[2];
  const float* c2w  = (const float*)d_in[3];
  const float* c2b  = (const float*)d_in[4];
  const float* c3w  = (const float*)d_in[5];
  const float* c3b  = (const float*)d_in[6];
  const float* bn1g = (const float*)d_in[7];
  const float* bn1b = (const float*)d_in[8];
  const float* bn1m = (const float*)d_in[9];
  const float* bn1v = (const float*)d_in[10];
  const float* c4w  = (const float*)d_in[11];
  const float* c4b  = (const float*)d_in[12];
  const float* c5w  = (const float*)d_in[13];
  const float* c5b  = (const float*)d_in[14];
  const float* bn2g = (const float*)d_in[15];
  const float* bn2b = (const float*)d_in[16];
  const float* bn2m = (const float*)d_in[17];
  const float* bn2v = (const float*)d_in[18];
  const float* c6w  = (const float*)d_in[19];
  const float* c6b  = (const float*)d_in[20];
  const float* bn3g = (const float*)d_in[21];
  const float* bn3b = (const float*)d_in[22];
  const float* bn3m = (const float*)d_in[23];
  const float* bn3v = (const float*)d_in[24];
  const float* wihf = (const float*)d_in[25];
  const float* whhf = (const float*)d_in[26];
  const float* bihf = (const float*)d_in[27];
  const float* bhhf = (const float*)d_in[28];
  const float* wihb = (const float*)d_in[29];
  const float* whhb = (const float*)d_in[30];
  const float* bihb = (const float*)d_in[31];
  const float* bhhb = (const float*)d_in[32];

  float* ws = (float*)d_ws;
  typedef unsigned short u16;

  float* pre  = ws;                                   // 39,976,960 f
  u16*   y3H  = (u16*)(ws);            u16* y3L = y3H + 15026176ull;
  u16*   y4H  = (u16*)(ws + 15100000ull); u16* y4L = y4H + 13879296ull;
  u16*   p1H  = (u16*)(ws + 29000000ull); u16* p1L = p1H + 8094720ull;
  u16*   p2H  = (u16*)(ws);            u16* p2L = p2H + 13312000ull;
  u16*   p3H  = (u16*)(ws + 15100000ull); u16* p3L = p3H + 6094848ull;
  u16*   rowsL= (u16*)(ws + 40000000ull);             // 9,994,240 u
  unsigned* UPd = (unsigned*)(ws + 45100000ull);      // 262,144 u32 (packed f16x2)
  u16*   W3H  = (u16*)(ws + 45650000ull); u16* W3L = (u16*)(ws + 45800000ull);
  u16*   W4H  = (u16*)(ws + 45950000ull); u16* W4L = (u16*)(ws + 46250000ull);
  u16*   W5H  = (u16*)(ws + 46550000ull); u16* W5L = (u16*)(ws + 47150000ull);
  u16*   W6H  = (u16*)(ws + 47750000ull); u16* W6L = (u16*)(ws + 48950000ull);
  u16*   WgfH = (u16*)(ws + 50150000ull); u16* WgfL = (u16*)(ws + 50450000ull);
  u16*   WgbH = (u16*)(ws + 50750000ull); u16* WgbL = (u16*)(ws + 51050000ull);
  float* b3   = ws + 51350000ull;
  float* b4   = ws + 51360000ull;
  float* b5   = ws + 51370000ull;
  float* b6   = ws + 51380000ull;
  float* bgf  = ws + 51390000ull;
  float* bgb  = ws + 51400000ull;
  float* weff = ws + 51420000ull;
  float* beff = ws + 51430000ull;
  u16*   rowsH = (u16*)d_out;                         // 9,994,240 u (in d_out)
  float* outF  = (float*)d_out;

  // ---- weight preparation ----
  k_fold<<<1, 256, 0, stream>>>(c1w, c1b, c2w, c2b, weff, beff);
  k_prepW<<<1152, 256, 0, stream>>>(c3w, c3b, bn1g,bn1b,bn1m,bn1v, 1, 256,128, W3H,W3L, b3);
  k_prepW<<<2304, 256, 0, stream>>>(c4w, c4b, nullptr,nullptr,nullptr,nullptr, 0, 256,256, W4H,W4L, b4);
  k_prepW<<<4608, 256, 0, stream>>>(c5w, c5b, bn2g,bn2b,bn2m,bn2v, 1, 512,256, W5H,W5L, b5);
  k_prepW<<<9216, 256, 0, stream>>>(c6w, c6b, bn3g,bn3b,bn3m,bn3v, 1, 512,512, W6H,W6L, b6);
  k_prepWg<<<2048, 256, 0, stream>>>(wihf, bihf, bhhf, WgfH, WgfL, bgf);
  k_prepWg<<<2048, 256, 0, stream>>>(wihb, bihb, bhhb, WgbH, WgbL, bgb);
  k_prepU<<<1024, 256, 0, stream>>>(whhf, whhb, UPd);

  // ---- conv chain, two batch-halves of 8 images ----
  for (int hb = 0; hb < 2; ++hb){
    int nB = hb*8;
    const float* xh = x + (size_t)nB*98304ull;
    k_conv2pool<<<dim3(8,16,128), 256, 0, stream>>>(xh, weff, beff, p1H, p1L);
    k_igemm<<<dim3(2,29,16), 256, 0, stream>>>(p1H,p1L, W3H,W3L, b3,
        y3H,y3L, nullptr, 31,255,128,256,29,253, 9,0,4);
    k_igemm<<<dim3(2,27,16), 256, 0, stream>>>(y3H,y3L, W4H,W4L, b4,
        y4H,y4L, nullptr, 29,253,256,256,27,251, 9,0,8);
    k_pool2<<<6500, 256, 0, stream>>>(y4H,y4L, p2H,p2L);
    k_igemm<<<dim3(1,12,32), 256, 0, stream>>>(p2H,p2L, W5H,W5L, b5,
        p3H,p3L, nullptr, 26,250,256,512,12,124, 9,1,8);
    k_igemm<<<dim3(1,10,32), 256, 0, stream>>>(p3H,p3L, W6H,W6L, b6,
        rowsH + (size_t)nB*624640ull, rowsL + (size_t)nB*624640ull, nullptr,
        12,124,512,512,10,122, 9,0,16);
  }

  // ---- input projection GEMMs: rows(19520x512) @ W^T(512x1024) -> pre fp32 ----
  k_igemm<<<dim3(153,1,8), 256, 0, stream>>>(rowsH,rowsL, WgfH,WgfL, bgf,
      nullptr,nullptr, pre, 1,19520,512,1024,1,19520, 1,0,16);
  k_igemm<<<dim3(153,1,8), 256, 0, stream>>>(rowsH,rowsL, WgbH,WgbL, bgb,
      nullptr,nullptr, pre + 19988480ull, 1,19520,512,1024,1,19520, 1,0,16);

  // ---- recurrence (scalar, f16x2-packed U) ----
  k_lstm<<<160, 1024, 0, stream>>>(pre, UPd, outF);
}